// Round 1
// baseline (4060.632 us; speedup 1.0000x reference)
//
#include <hip/hip_runtime.h>
#include <hip/hip_bf16.h>
#include <stdint.h>
#include <stddef.h>

#define NN   100000   // nodes
#define NE   1600000  // edges
#define INC  512      // in channels
#define HID  256      // hidden
#define OC   40       // out channels
#define OCP  48       // padded out channels (3 x 16 col-tiles)

typedef __bf16 bf16_t;
typedef __bf16 bf16x8 __attribute__((ext_vector_type(8)));
typedef __bf16 bf16x4 __attribute__((ext_vector_type(4)));
typedef float  f32x4  __attribute__((ext_vector_type(4)));

// ---- device-global scratch (avoids ws_size assumptions; ~290 MB) ----
__device__ unsigned g_amax_bits[4];          // 0:x 1:w1 2:w2 3:h  (float bits, >=0)
__device__ unsigned g_deg[NN];
__device__ float    g_dinv[NN];
__device__ bf16_t   g_qx[(size_t)NN * INC];  // quantized x as bf16 ints
__device__ bf16_t   g_qw1[HID * INC];
__device__ bf16_t   g_qw2[OCP * HID];        // rows 40..47 zero
__device__ float    g_h[(size_t)NN * HID];   // relu(fc1) fp32
__device__ bf16_t   g_qh[(size_t)NN * HID];  // quantized h as bf16 ints
__device__ float    g_z[(size_t)NN * OC];    // fc2 output
__device__ float    g_zout[(size_t)NN * OC]; // propagated

// ---------------- init: zero all accumulated state ----------------
__global__ void init_kernel() {
    int idx = blockIdx.x * blockDim.x + threadIdx.x;
    int stride = gridDim.x * blockDim.x;
    for (int i = idx; i < NN * OC; i += stride) g_zout[i] = 0.0f;
    for (int i = idx; i < NN; i += stride) g_deg[i] = 0u;
    for (int i = idx; i < OCP * HID; i += stride) g_qw2[i] = (bf16_t)0.0f;
    if (idx < 4) g_amax_bits[idx] = 0u;
}

// ---------------- absmax reduction (float4 loads) ----------------
__global__ void absmax_kernel(const float* __restrict__ src, int n4, int slot) {
    int idx = blockIdx.x * blockDim.x + threadIdx.x;
    int stride = gridDim.x * blockDim.x;
    const f32x4* s4 = (const f32x4*)src;
    float m = 0.0f;
    for (int i = idx; i < n4; i += stride) {
        f32x4 v = s4[i];
        m = fmaxf(m, fmaxf(fmaxf(fabsf(v.x), fabsf(v.y)),
                           fmaxf(fabsf(v.z), fabsf(v.w))));
    }
#pragma unroll
    for (int off = 32; off > 0; off >>= 1) m = fmaxf(m, __shfl_xor(m, off, 64));
    __shared__ float sm[4];
    if ((threadIdx.x & 63) == 0) sm[threadIdx.x >> 6] = m;
    __syncthreads();
    if (threadIdx.x == 0) {
        float mm = fmaxf(fmaxf(sm[0], sm[1]), fmaxf(sm[2], sm[3]));
        atomicMax(&g_amax_bits[slot], __float_as_uint(mm));
    }
}

// ------------- quantize to bf16-exact ints in [-128,127] -------------
// which: 0 -> g_qx, 1 -> g_qw1, 2 -> g_qw2, 3 -> (src=g_h) -> g_qh
__global__ void quant_kernel(const float* __restrict__ srcp, int n4, int slot, int which) {
    const float* src = (which == 3) ? g_h : srcp;
    bf16_t* dst = (which == 0) ? g_qx : (which == 1) ? g_qw1 : (which == 2) ? g_qw2 : g_qh;
    float scale = __uint_as_float(g_amax_bits[slot]) / 127.0f + 1e-12f;
    int idx = blockIdx.x * blockDim.x + threadIdx.x;
    int stride = gridDim.x * blockDim.x;
    const f32x4* s4 = (const f32x4*)src;
    bf16x4* d4 = (bf16x4*)dst;
    for (int i = idx; i < n4; i += stride) {
        f32x4 v = s4[i];
        float q0 = fminf(fmaxf(rintf(v.x / scale), -128.0f), 127.0f);
        float q1 = fminf(fmaxf(rintf(v.y / scale), -128.0f), 127.0f);
        float q2 = fminf(fmaxf(rintf(v.z / scale), -128.0f), 127.0f);
        float q3 = fminf(fmaxf(rintf(v.w / scale), -128.0f), 127.0f);
        bf16x4 o;
        o[0] = (bf16_t)q0; o[1] = (bf16_t)q1; o[2] = (bf16_t)q2; o[3] = (bf16_t)q3;
        d4[i] = o;
    }
}

// ---------------- GEMM1: h = relu(qx @ qw1^T * s + b1), amax(h) ----------------
// block = 256 (4 waves); each wave: 16 rows x 256 cols (16 col-tiles of 16x16)
__launch_bounds__(256)
__global__ void gemm1_kernel(const float* __restrict__ b1) {
    int wave = threadIdx.x >> 6;
    int lane = threadIdx.x & 63;
    int quad = lane >> 4;
    int l16  = lane & 15;
    int row_base = blockIdx.x * 64 + wave * 16;
    int arow = row_base + l16; if (arow >= NN) arow = NN - 1;
    const bf16_t* aptr = g_qx + (size_t)arow * INC + quad * 8;

    f32x4 acc[16] = {};
#pragma unroll 2
    for (int ks = 0; ks < 16; ks++) {
        bf16x8 a = *(const bf16x8*)(aptr + ks * 32);
#pragma unroll
        for (int ct = 0; ct < 16; ct++) {
            bf16x8 b = *(const bf16x8*)(g_qw1 + (ct * 16 + l16) * INC + ks * 32 + quad * 8);
            acc[ct] = __builtin_amdgcn_mfma_f32_16x16x32_bf16(a, b, acc[ct], 0, 0, 0);
        }
    }
    float s = (__uint_as_float(g_amax_bits[0]) / 127.0f + 1e-12f)
            * (__uint_as_float(g_amax_bits[1]) / 127.0f + 1e-12f);
    float lmax = 0.0f;
#pragma unroll
    for (int ct = 0; ct < 16; ct++) {
        int c = ct * 16 + l16;
        float bias = b1[c];
#pragma unroll
        for (int i = 0; i < 4; i++) {
            int r = row_base + quad * 4 + i;
            float v = fmaxf(s * acc[ct][i] + bias, 0.0f);
            if (r < NN) { g_h[(size_t)r * HID + c] = v; lmax = fmaxf(lmax, v); }
        }
    }
#pragma unroll
    for (int off = 32; off > 0; off >>= 1) lmax = fmaxf(lmax, __shfl_xor(lmax, off, 64));
    if (lane == 0) atomicMax(&g_amax_bits[3], __float_as_uint(lmax));
}

// ---------------- GEMM2: z = qh @ qw2^T * s + b2 ----------------
__launch_bounds__(256)
__global__ void gemm2_kernel(const float* __restrict__ b2) {
    int wave = threadIdx.x >> 6;
    int lane = threadIdx.x & 63;
    int quad = lane >> 4;
    int l16  = lane & 15;
    int row_base = blockIdx.x * 64 + wave * 16;
    int arow = row_base + l16; if (arow >= NN) arow = NN - 1;
    const bf16_t* aptr = g_qh + (size_t)arow * HID + quad * 8;

    f32x4 acc[3] = {};
#pragma unroll
    for (int ks = 0; ks < 8; ks++) {
        bf16x8 a = *(const bf16x8*)(aptr + ks * 32);
#pragma unroll
        for (int ct = 0; ct < 3; ct++) {
            bf16x8 b = *(const bf16x8*)(g_qw2 + (ct * 16 + l16) * HID + ks * 32 + quad * 8);
            acc[ct] = __builtin_amdgcn_mfma_f32_16x16x32_bf16(a, b, acc[ct], 0, 0, 0);
        }
    }
    float s = (__uint_as_float(g_amax_bits[3]) / 127.0f + 1e-12f)
            * (__uint_as_float(g_amax_bits[2]) / 127.0f + 1e-12f);
#pragma unroll
    for (int ct = 0; ct < 3; ct++) {
        int c = ct * 16 + l16;
#pragma unroll
        for (int i = 0; i < 4; i++) {
            int r = row_base + quad * 4 + i;
            if (c < OC && r < NN) g_z[(size_t)r * OC + c] = s * acc[ct][i] + b2[c];
        }
    }
}

// ---------------- degree histogram ----------------
__global__ void deg_kernel(const int* __restrict__ ei) {
    const int* dst = ei + NE;
    int idx = blockIdx.x * blockDim.x + threadIdx.x;
    int stride = gridDim.x * blockDim.x;
    for (int e = idx; e < NE; e += stride) atomicAdd(&g_deg[dst[e]], 1u);
}

__global__ void dinv_kernel() {
    int idx = blockIdx.x * blockDim.x + threadIdx.x;
    int stride = gridDim.x * blockDim.x;
    for (int i = idx; i < NN; i += stride) {
        unsigned d = g_deg[i];
        g_dinv[i] = d ? rsqrtf((float)d) : 0.0f;
    }
}

// ---------------- edge scatter: zout[dst] += z[src] * dinv[src]*dinv[dst] ----------------
__global__ void scatter_kernel(const int* __restrict__ ei) {
    const int* srcp = ei;
    const int* dstp = ei + NE;
    int idx = blockIdx.x * blockDim.x + threadIdx.x;
    int stride = gridDim.x * blockDim.x;
    for (int e = idx; e < NE; e += stride) {
        int s = srcp[e], d = dstp[e];
        float c = g_dinv[s] * g_dinv[d];
        const f32x4* zs = (const f32x4*)(g_z + (size_t)s * OC);
        float* zo = g_zout + (size_t)d * OC;
#pragma unroll
        for (int j = 0; j < 10; j++) {
            f32x4 v = zs[j];
            atomicAdd(zo + j * 4 + 0, v.x * c);
            atomicAdd(zo + j * 4 + 1, v.y * c);
            atomicAdd(zo + j * 4 + 2, v.z * c);
            atomicAdd(zo + j * 4 + 3, v.w * c);
        }
    }
}

// ---------------- log_softmax over 40 channels ----------------
__global__ void lsm_kernel(float* __restrict__ out) {
    int idx = blockIdx.x * blockDim.x + threadIdx.x;
    int stride = gridDim.x * blockDim.x;
    for (int i = idx; i < NN; i += stride) {
        const f32x4* zi = (const f32x4*)(g_zout + (size_t)i * OC);
        float v[OC];
#pragma unroll
        for (int j = 0; j < 10; j++) {
            f32x4 t = zi[j];
            v[j * 4 + 0] = t.x; v[j * 4 + 1] = t.y;
            v[j * 4 + 2] = t.z; v[j * 4 + 3] = t.w;
        }
        float m = -1e30f;
#pragma unroll
        for (int j = 0; j < OC; j++) m = fmaxf(m, v[j]);
        float ssum = 0.0f;
#pragma unroll
        for (int j = 0; j < OC; j++) ssum += expf(v[j] - m);
        float lg = logf(ssum);
        f32x4* o = (f32x4*)(out + (size_t)i * OC);
#pragma unroll
        for (int j = 0; j < 10; j++) {
            f32x4 t;
            t.x = v[j * 4 + 0] - m - lg; t.y = v[j * 4 + 1] - m - lg;
            t.z = v[j * 4 + 2] - m - lg; t.w = v[j * 4 + 3] - m - lg;
            o[j] = t;
        }
    }
}

extern "C" void kernel_launch(void* const* d_in, const int* in_sizes, int n_in,
                              void* d_out, int out_size, void* d_ws, size_t ws_size,
                              hipStream_t stream) {
    const float* x  = (const float*)d_in[0];
    const int*   ei = (const int*)d_in[1];
    const float* w1 = (const float*)d_in[2];
    const float* b1 = (const float*)d_in[3];
    const float* w2 = (const float*)d_in[4];
    const float* b2 = (const float*)d_in[5];
    float* out = (float*)d_out;
    (void)d_ws; (void)ws_size; (void)in_sizes; (void)n_in; (void)out_size;

    init_kernel<<<4096, 256, 0, stream>>>();
    absmax_kernel<<<2048, 256, 0, stream>>>(x,  (NN * INC) / 4, 0);
    absmax_kernel<<<128, 256, 0, stream>>>(w1, (HID * INC) / 4, 1);
    absmax_kernel<<<10, 256, 0, stream>>>(w2,  (OC * HID) / 4, 2);
    quant_kernel<<<2048, 256, 0, stream>>>(x,  (NN * INC) / 4, 0, 0);
    quant_kernel<<<128, 256, 0, stream>>>(w1, (HID * INC) / 4, 1, 1);
    quant_kernel<<<10, 256, 0, stream>>>(w2,  (OC * HID) / 4, 2, 2);
    gemm1_kernel<<<(NN + 63) / 64, 256, 0, stream>>>(b1);
    quant_kernel<<<2048, 256, 0, stream>>>(nullptr, (NN * HID) / 4, 3, 3);
    gemm2_kernel<<<(NN + 63) / 64, 256, 0, stream>>>(b2);
    deg_kernel<<<2048, 256, 0, stream>>>(ei);
    dinv_kernel<<<391, 256, 0, stream>>>();
    scatter_kernel<<<6250, 256, 0, stream>>>(ei);
    lsm_kernel<<<391, 256, 0, stream>>>(out);
}

// Round 2
// 989.989 us; speedup vs baseline: 4.1017x; 4.1017x over previous
//
#include <hip/hip_runtime.h>
#include <hip/hip_bf16.h>
#include <stdint.h>
#include <stddef.h>

#define NN   100000   // nodes
#define NE   1600000  // edges
#define INC  512      // in channels
#define HID  256      // hidden
#define OC   40       // out channels
#define OCP  48       // padded out channels (3 x 16 col-tiles)

#define SCAN_TILE 1024
#define SCAN_NB  ((NN + SCAN_TILE - 1) / SCAN_TILE)   // 98

typedef __bf16 bf16_t;
typedef __bf16 bf16x8 __attribute__((ext_vector_type(8)));
typedef __bf16 bf16x4 __attribute__((ext_vector_type(4)));
typedef float  f32x4  __attribute__((ext_vector_type(4)));

// ---- device-global scratch ----
__device__ unsigned g_amax_bits[4];          // 0:x 1:w1 2:w2 3:h  (float bits, >=0)
__device__ unsigned g_deg[NN];
__device__ float    g_dinv[NN];
__device__ bf16_t   g_qx[(size_t)NN * INC];  // quantized x as bf16 ints
__device__ bf16_t   g_qw1[HID * INC];
__device__ bf16_t   g_qw2[OCP * HID];        // rows 40..47 zero
__device__ float    g_h[(size_t)NN * HID];   // relu(fc1) fp32
__device__ bf16_t   g_qh[(size_t)NN * HID];  // quantized h as bf16 ints
__device__ float    g_z[(size_t)NN * OC];    // fc2 output (16 MB -> L2/L3 resident)
// CSR-by-destination
__device__ unsigned g_rowtmp[NN];
__device__ unsigned g_rowstart[NN + 1];
__device__ unsigned g_cursor[NN];
__device__ unsigned g_bsum[SCAN_NB];
__device__ unsigned g_boff[SCAN_NB];
__device__ int      g_csr_src[NE];

// ---------------- init: zero all accumulated state ----------------
__global__ void init_kernel() {
    int idx = blockIdx.x * blockDim.x + threadIdx.x;
    int stride = gridDim.x * blockDim.x;
    for (int i = idx; i < NN; i += stride) g_deg[i] = 0u;
    for (int i = idx; i < OCP * HID; i += stride) g_qw2[i] = (bf16_t)0.0f;
    if (idx < 4) g_amax_bits[idx] = 0u;
}

// ---------------- absmax reduction (float4 loads) ----------------
__global__ void absmax_kernel(const float* __restrict__ src, int n4, int slot) {
    int idx = blockIdx.x * blockDim.x + threadIdx.x;
    int stride = gridDim.x * blockDim.x;
    const f32x4* s4 = (const f32x4*)src;
    float m = 0.0f;
    for (int i = idx; i < n4; i += stride) {
        f32x4 v = s4[i];
        m = fmaxf(m, fmaxf(fmaxf(fabsf(v.x), fabsf(v.y)),
                           fmaxf(fabsf(v.z), fabsf(v.w))));
    }
#pragma unroll
    for (int off = 32; off > 0; off >>= 1) m = fmaxf(m, __shfl_xor(m, off, 64));
    __shared__ float sm[4];
    if ((threadIdx.x & 63) == 0) sm[threadIdx.x >> 6] = m;
    __syncthreads();
    if (threadIdx.x == 0) {
        float mm = fmaxf(fmaxf(sm[0], sm[1]), fmaxf(sm[2], sm[3]));
        atomicMax(&g_amax_bits[slot], __float_as_uint(mm));
    }
}

// ------------- quantize to bf16-exact ints in [-128,127] -------------
// which: 0 -> g_qx, 1 -> g_qw1, 2 -> g_qw2, 3 -> (src=g_h) -> g_qh
__global__ void quant_kernel(const float* __restrict__ srcp, int n4, int slot, int which) {
    const float* src = (which == 3) ? g_h : srcp;
    bf16_t* dst = (which == 0) ? g_qx : (which == 1) ? g_qw1 : (which == 2) ? g_qw2 : g_qh;
    float scale = __uint_as_float(g_amax_bits[slot]) / 127.0f + 1e-12f;
    int idx = blockIdx.x * blockDim.x + threadIdx.x;
    int stride = gridDim.x * blockDim.x;
    const f32x4* s4 = (const f32x4*)src;
    bf16x4* d4 = (bf16x4*)dst;
    for (int i = idx; i < n4; i += stride) {
        f32x4 v = s4[i];
        float q0 = fminf(fmaxf(rintf(v.x / scale), -128.0f), 127.0f);
        float q1 = fminf(fmaxf(rintf(v.y / scale), -128.0f), 127.0f);
        float q2 = fminf(fmaxf(rintf(v.z / scale), -128.0f), 127.0f);
        float q3 = fminf(fmaxf(rintf(v.w / scale), -128.0f), 127.0f);
        bf16x4 o;
        o[0] = (bf16_t)q0; o[1] = (bf16_t)q1; o[2] = (bf16_t)q2; o[3] = (bf16_t)q3;
        d4[i] = o;
    }
}

// ---------------- GEMM1: h = relu(qx @ qw1^T * s + b1), amax(h) ----------------
__launch_bounds__(256)
__global__ void gemm1_kernel(const float* __restrict__ b1) {
    int wave = threadIdx.x >> 6;
    int lane = threadIdx.x & 63;
    int quad = lane >> 4;
    int l16  = lane & 15;
    int row_base = blockIdx.x * 64 + wave * 16;
    int arow = row_base + l16; if (arow >= NN) arow = NN - 1;
    const bf16_t* aptr = g_qx + (size_t)arow * INC + quad * 8;

    f32x4 acc[16] = {};
#pragma unroll 2
    for (int ks = 0; ks < 16; ks++) {
        bf16x8 a = *(const bf16x8*)(aptr + ks * 32);
#pragma unroll
        for (int ct = 0; ct < 16; ct++) {
            bf16x8 b = *(const bf16x8*)(g_qw1 + (ct * 16 + l16) * INC + ks * 32 + quad * 8);
            acc[ct] = __builtin_amdgcn_mfma_f32_16x16x32_bf16(a, b, acc[ct], 0, 0, 0);
        }
    }
    float s = (__uint_as_float(g_amax_bits[0]) / 127.0f + 1e-12f)
            * (__uint_as_float(g_amax_bits[1]) / 127.0f + 1e-12f);
    float lmax = 0.0f;
#pragma unroll
    for (int ct = 0; ct < 16; ct++) {
        int c = ct * 16 + l16;
        float bias = b1[c];
#pragma unroll
        for (int i = 0; i < 4; i++) {
            int r = row_base + quad * 4 + i;
            float v = fmaxf(s * acc[ct][i] + bias, 0.0f);
            if (r < NN) { g_h[(size_t)r * HID + c] = v; lmax = fmaxf(lmax, v); }
        }
    }
#pragma unroll
    for (int off = 32; off > 0; off >>= 1) lmax = fmaxf(lmax, __shfl_xor(lmax, off, 64));
    if (lane == 0) atomicMax(&g_amax_bits[3], __float_as_uint(lmax));
}

// ---------------- GEMM2: z = qh @ qw2^T * s + b2 ----------------
__launch_bounds__(256)
__global__ void gemm2_kernel(const float* __restrict__ b2) {
    int wave = threadIdx.x >> 6;
    int lane = threadIdx.x & 63;
    int quad = lane >> 4;
    int l16  = lane & 15;
    int row_base = blockIdx.x * 64 + wave * 16;
    int arow = row_base + l16; if (arow >= NN) arow = NN - 1;
    const bf16_t* aptr = g_qh + (size_t)arow * HID + quad * 8;

    f32x4 acc[3] = {};
#pragma unroll
    for (int ks = 0; ks < 8; ks++) {
        bf16x8 a = *(const bf16x8*)(aptr + ks * 32);
#pragma unroll
        for (int ct = 0; ct < 3; ct++) {
            bf16x8 b = *(const bf16x8*)(g_qw2 + (ct * 16 + l16) * HID + ks * 32 + quad * 8);
            acc[ct] = __builtin_amdgcn_mfma_f32_16x16x32_bf16(a, b, acc[ct], 0, 0, 0);
        }
    }
    float s = (__uint_as_float(g_amax_bits[3]) / 127.0f + 1e-12f)
            * (__uint_as_float(g_amax_bits[2]) / 127.0f + 1e-12f);
#pragma unroll
    for (int ct = 0; ct < 3; ct++) {
        int c = ct * 16 + l16;
#pragma unroll
        for (int i = 0; i < 4; i++) {
            int r = row_base + quad * 4 + i;
            if (c < OC && r < NN) g_z[(size_t)r * OC + c] = s * acc[ct][i] + b2[c];
        }
    }
}

// ---------------- degree histogram ----------------
__global__ void deg_kernel(const int* __restrict__ ei) {
    const int* dst = ei + NE;
    int idx = blockIdx.x * blockDim.x + threadIdx.x;
    int stride = gridDim.x * blockDim.x;
    for (int e = idx; e < NE; e += stride) atomicAdd(&g_deg[dst[e]], 1u);
}

__global__ void dinv_kernel() {
    int idx = blockIdx.x * blockDim.x + threadIdx.x;
    int stride = gridDim.x * blockDim.x;
    for (int i = idx; i < NN; i += stride) {
        unsigned d = g_deg[i];
        g_dinv[i] = d ? rsqrtf((float)d) : 0.0f;
    }
}

// ---------------- scan phase 1: per-1024-tile exclusive scan ----------------
__global__ void scan1_kernel() {
    int blk = blockIdx.x, t = threadIdx.x;
    int base = blk * SCAN_TILE + t * 4;
    unsigned v[4]; unsigned s = 0;
#pragma unroll
    for (int j = 0; j < 4; j++) { int i = base + j; v[j] = (i < NN) ? g_deg[i] : 0u; s += v[j]; }
    int lane = t & 63, wv = t >> 6;
    unsigned sc = s;
#pragma unroll
    for (int off = 1; off < 64; off <<= 1) {
        unsigned n = __shfl_up(sc, off, 64);
        if (lane >= off) sc += n;
    }
    __shared__ unsigned wsum[4];
    if (lane == 63) wsum[wv] = sc;
    __syncthreads();
    unsigned woff = 0;
    for (int w = 0; w < 4; w++) if (w < wv) woff += wsum[w];
    unsigned run = woff + sc - s;   // exclusive prefix of this thread's chunk
#pragma unroll
    for (int j = 0; j < 4; j++) { int i = base + j; if (i < NN) g_rowtmp[i] = run; run += v[j]; }
    if (t == 255) g_bsum[blk] = woff + sc;
}

// ---------------- scan phase 2: scan the 98 block sums (1 block) ----------------
__global__ void scan2_kernel() {
    int t = threadIdx.x;
    unsigned v = (t < SCAN_NB) ? g_bsum[t] : 0u;
    int lane = t & 63, wv = t >> 6;
    unsigned sc = v;
#pragma unroll
    for (int off = 1; off < 64; off <<= 1) {
        unsigned n = __shfl_up(sc, off, 64);
        if (lane >= off) sc += n;
    }
    __shared__ unsigned ws[2];
    if (lane == 63) ws[wv] = sc;
    __syncthreads();
    unsigned excl = sc - v + (wv ? ws[0] : 0u);
    if (t < SCAN_NB) g_boff[t] = excl;
}

// ---------------- scan phase 3: add block offsets, init cursor ----------------
__global__ void scan3_kernel() {
    int i = blockIdx.x * blockDim.x + threadIdx.x;
    if (i < NN) {
        unsigned r = g_rowtmp[i] + g_boff[i / SCAN_TILE];
        g_rowstart[i] = r;
        g_cursor[i] = r;
    }
    if (i == 0) g_rowstart[NN] = NE;
}

// ---------------- CSR bucket fill ----------------
__global__ void fill_kernel(const int* __restrict__ ei) {
    const int* srcp = ei;
    const int* dstp = ei + NE;
    int idx = blockIdx.x * blockDim.x + threadIdx.x;
    int stride = gridDim.x * blockDim.x;
    for (int e = idx; e < NE; e += stride) {
        int d = dstp[e];
        unsigned pos = atomicAdd(&g_cursor[d], 1u);
        g_csr_src[pos] = srcp[e];
    }
}

// ---------------- gather + fused log_softmax: one wave per node ----------------
__launch_bounds__(256)
__global__ void gather_kernel(float* __restrict__ out) {
    int node = (blockIdx.x * 256 + threadIdx.x) >> 6;
    int lane = threadIdx.x & 63;
    if (node >= NN) return;
    unsigned e0 = g_rowstart[node], e1 = g_rowstart[node + 1];
    float dinvd = g_dinv[node];
    float acc = 0.0f;
    unsigned e = e0;
    // unroll-by-2 for ILP on the dependent load chain
    for (; e + 2 <= e1; e += 2) {
        int s0 = g_csr_src[e], s1 = g_csr_src[e + 1];
        float c0 = g_dinv[s0] * dinvd;
        float c1 = g_dinv[s1] * dinvd;
        float z0 = (lane < OC) ? g_z[(size_t)s0 * OC + lane] : 0.0f;
        float z1 = (lane < OC) ? g_z[(size_t)s1 * OC + lane] : 0.0f;
        acc += z0 * c0 + z1 * c1;
    }
    if (e < e1) {
        int s0 = g_csr_src[e];
        float c0 = g_dinv[s0] * dinvd;
        float z0 = (lane < OC) ? g_z[(size_t)s0 * OC + lane] : 0.0f;
        acc += z0 * c0;
    }
    // fused log_softmax across lanes 0..39
    float m = (lane < OC) ? acc : -1e30f;
#pragma unroll
    for (int off = 32; off > 0; off >>= 1) m = fmaxf(m, __shfl_xor(m, off, 64));
    float ex = (lane < OC) ? __expf(acc - m) : 0.0f;
    float ssum = ex;
#pragma unroll
    for (int off = 32; off > 0; off >>= 1) ssum += __shfl_xor(ssum, off, 64);
    float lg = __logf(ssum);
    if (lane < OC) out[(size_t)node * OC + lane] = acc - m - lg;
}

extern "C" void kernel_launch(void* const* d_in, const int* in_sizes, int n_in,
                              void* d_out, int out_size, void* d_ws, size_t ws_size,
                              hipStream_t stream) {
    const float* x  = (const float*)d_in[0];
    const int*   ei = (const int*)d_in[1];
    const float* w1 = (const float*)d_in[2];
    const float* b1 = (const float*)d_in[3];
    const float* w2 = (const float*)d_in[4];
    const float* b2 = (const float*)d_in[5];
    float* out = (float*)d_out;
    (void)d_ws; (void)ws_size; (void)in_sizes; (void)n_in; (void)out_size;

    init_kernel<<<1024, 256, 0, stream>>>();
    // graph topology pipeline (independent of feature pipeline)
    deg_kernel<<<2048, 256, 0, stream>>>(ei);
    dinv_kernel<<<391, 256, 0, stream>>>();
    scan1_kernel<<<SCAN_NB, 256, 0, stream>>>();
    scan2_kernel<<<1, 128, 0, stream>>>();
    scan3_kernel<<<391, 256, 0, stream>>>();
    fill_kernel<<<2048, 256, 0, stream>>>(ei);
    // feature pipeline
    absmax_kernel<<<2048, 256, 0, stream>>>(x,  (NN * INC) / 4, 0);
    absmax_kernel<<<128, 256, 0, stream>>>(w1, (HID * INC) / 4, 1);
    absmax_kernel<<<10, 256, 0, stream>>>(w2,  (OC * HID) / 4, 2);
    quant_kernel<<<2048, 256, 0, stream>>>(x,  (NN * INC) / 4, 0, 0);
    quant_kernel<<<128, 256, 0, stream>>>(w1, (HID * INC) / 4, 1, 1);
    quant_kernel<<<10, 256, 0, stream>>>(w2,  (OC * HID) / 4, 2, 2);
    gemm1_kernel<<<(NN + 63) / 64, 256, 0, stream>>>(b1);
    quant_kernel<<<2048, 256, 0, stream>>>(nullptr, (NN * HID) / 4, 3, 3);
    gemm2_kernel<<<(NN + 63) / 64, 256, 0, stream>>>(b2);
    // propagation: gather + fused log_softmax
    gather_kernel<<<(NN + 3) / 4, 256, 0, stream>>>(out);
}

// Round 3
// 781.241 us; speedup vs baseline: 5.1977x; 1.2672x over previous
//
#include <hip/hip_runtime.h>
#include <hip/hip_bf16.h>
#include <stdint.h>
#include <stddef.h>

#define NN   100000   // nodes
#define NE   1600000  // edges
#define INC  512      // in channels
#define HID  256      // hidden
#define OC   40       // out channels
#define OCP  48       // padded out channels (3 x 16 col-tiles)

#define SCAN_TILE 1024
#define SCAN_NB  ((NN + SCAN_TILE - 1) / SCAN_TILE)   // 98

typedef __bf16 bf16_t;
typedef __bf16 bf16x8 __attribute__((ext_vector_type(8)));
typedef __bf16 bf16x4 __attribute__((ext_vector_type(4)));
typedef float  f32x4  __attribute__((ext_vector_type(4)));

#define GLOAD_LDS16(gp, lp) __builtin_amdgcn_global_load_lds( \
    (const __attribute__((address_space(1))) uint32_t*)(gp),  \
    (__attribute__((address_space(3))) uint32_t*)(lp), 16, 0, 0)

// ---- device-global scratch ----
__device__ unsigned g_amax_bits[4];          // 0:x 1:w1 2:w2 3:h
__device__ unsigned g_deg[NN];
__device__ float    g_dinv[NN];
__device__ bf16_t   g_qw1[HID * INC];
__device__ bf16_t   g_qw2[OCP * HID];        // rows 40..47 zero
__device__ float    g_h[(size_t)NN * HID];   // relu(fc1) fp32
__device__ float    g_z[(size_t)NN * OC];    // fc2 output (16 MB -> L2/L3 resident)
// CSR-by-destination
__device__ unsigned g_rowtmp[NN];
__device__ unsigned g_rowstart[NN + 1];
__device__ unsigned g_cursor[NN];
__device__ unsigned g_bsum[SCAN_NB];
__device__ unsigned g_boff[SCAN_NB];
__device__ int      g_csr_src[NE];

// ---------------- init ----------------
__global__ void init_kernel() {
    int idx = blockIdx.x * blockDim.x + threadIdx.x;
    int stride = gridDim.x * blockDim.x;
    for (int i = idx; i < NN; i += stride) g_deg[i] = 0u;
    for (int i = idx; i < OCP * HID; i += stride) g_qw2[i] = (bf16_t)0.0f;
    if (idx < 4) g_amax_bits[idx] = 0u;
}

// ---------------- absmax reduction ----------------
__global__ void absmax_kernel(const float* __restrict__ src, int n4, int slot) {
    int idx = blockIdx.x * blockDim.x + threadIdx.x;
    int stride = gridDim.x * blockDim.x;
    const f32x4* s4 = (const f32x4*)src;
    float m = 0.0f;
    for (int i = idx; i < n4; i += stride) {
        f32x4 v = s4[i];
        m = fmaxf(m, fmaxf(fmaxf(fabsf(v.x), fabsf(v.y)),
                           fmaxf(fabsf(v.z), fabsf(v.w))));
    }
#pragma unroll
    for (int off = 32; off > 0; off >>= 1) m = fmaxf(m, __shfl_xor(m, off, 64));
    __shared__ float sm[4];
    if ((threadIdx.x & 63) == 0) sm[threadIdx.x >> 6] = m;
    __syncthreads();
    if (threadIdx.x == 0) {
        float mm = fmaxf(fmaxf(sm[0], sm[1]), fmaxf(sm[2], sm[3]));
        atomicMax(&g_amax_bits[slot], __float_as_uint(mm));
    }
}

// ------------- quantize weights to bf16-exact ints (w1, w2 only; tiny) -------------
__global__ void quantw_kernel(const float* __restrict__ src, int n4, int slot, int which) {
    bf16_t* dst = which ? g_qw2 : g_qw1;
    float scale = __uint_as_float(g_amax_bits[slot]) / 127.0f + 1e-12f;
    float rs = 1.0f / scale;
    int idx = blockIdx.x * blockDim.x + threadIdx.x;
    int stride = gridDim.x * blockDim.x;
    const f32x4* s4 = (const f32x4*)src;
    bf16x4* d4 = (bf16x4*)dst;
    for (int i = idx; i < n4; i += stride) {
        f32x4 v = s4[i];
        bf16x4 o;
        o[0] = (bf16_t)fminf(fmaxf(rintf(v.x * rs), -128.0f), 127.0f);
        o[1] = (bf16_t)fminf(fmaxf(rintf(v.y * rs), -128.0f), 127.0f);
        o[2] = (bf16_t)fminf(fmaxf(rintf(v.z * rs), -128.0f), 127.0f);
        o[3] = (bf16_t)fminf(fmaxf(rintf(v.w * rs), -128.0f), 127.0f);
        d4[i] = o;
    }
}

// ---------------- GEMM1 fused: h = relu(fq(x) @ qw1^T * s + b1), amax(h) ----------------
// 128x128 tile, BK=64, 4 waves in 2x2; A: x fp32 -> quant -> LDS bf16; B: global_load_lds
__launch_bounds__(256)
__global__ void gemm1_kernel(const float* __restrict__ x, const float* __restrict__ b1) {
    __shared__ bf16_t lA[128 * 64];   // [row][k], stride 64
    __shared__ bf16_t lB[128 * 64];
    int t = threadIdx.x;
    int mtile = blockIdx.x >> 1, ntile = blockIdx.x & 1;
    int lane = t & 63, wv = t >> 6;
    int quad = lane >> 4, l16 = lane & 15;
    int mq = wv >> 1, nq = wv & 1;

    float scale_x = __uint_as_float(g_amax_bits[0]) / 127.0f + 1e-12f;
    float rs = 1.0f / scale_x;

    int arow_l = t >> 4;          // 0..15
    int acol   = (t & 15) * 4;    // 0..60
    int brow_l = t >> 3;          // 0..31
    int bcol   = (t & 7) * 8;     // elements

    f32x4 acc[4][4] = {};
#pragma unroll 1
    for (int kit = 0; kit < 8; kit++) {
        __syncthreads();
        // stage B (bf16, 128x64) via global_load_lds, 4 passes of 4KB
#pragma unroll
        for (int p = 0; p < 4; p++) {
            const bf16_t* gp = g_qw1 + (size_t)(ntile * 128 + p * 32 + brow_l) * INC
                               + kit * 64 + bcol;
            GLOAD_LDS16(gp, lB + (size_t)(p * 32 + brow_l) * 64 + bcol);
        }
        // stage A: x fp32 -> quantized bf16, 8 passes of 16 rows
#pragma unroll
        for (int p = 0; p < 8; p++) {
            int row = p * 16 + arow_l;
            int gr = mtile * 128 + row; if (gr >= NN) gr = NN - 1;
            f32x4 v = *(const f32x4*)(x + (size_t)gr * INC + kit * 64 + acol);
            bf16x4 o;
            o[0] = (bf16_t)fminf(fmaxf(rintf(v.x * rs), -128.0f), 127.0f);
            o[1] = (bf16_t)fminf(fmaxf(rintf(v.y * rs), -128.0f), 127.0f);
            o[2] = (bf16_t)fminf(fmaxf(rintf(v.z * rs), -128.0f), 127.0f);
            o[3] = (bf16_t)fminf(fmaxf(rintf(v.w * rs), -128.0f), 127.0f);
            *(bf16x4*)(lA + row * 64 + acol) = o;
        }
        __syncthreads();
#pragma unroll
        for (int k32 = 0; k32 < 2; k32++) {
            bf16x8 a[4], b[4];
#pragma unroll
            for (int i = 0; i < 4; i++)
                a[i] = *(const bf16x8*)(lA + (mq * 64 + i * 16 + l16) * 64 + k32 * 32 + quad * 8);
#pragma unroll
            for (int j = 0; j < 4; j++)
                b[j] = *(const bf16x8*)(lB + (nq * 64 + j * 16 + l16) * 64 + k32 * 32 + quad * 8);
#pragma unroll
            for (int i = 0; i < 4; i++)
#pragma unroll
                for (int j = 0; j < 4; j++)
                    acc[i][j] = __builtin_amdgcn_mfma_f32_16x16x32_bf16(a[i], b[j], acc[i][j], 0, 0, 0);
        }
    }
    float s = scale_x * (__uint_as_float(g_amax_bits[1]) / 127.0f + 1e-12f);
    float lmax = 0.0f;
#pragma unroll
    for (int j = 0; j < 4; j++) {
        int col = ntile * 128 + nq * 64 + j * 16 + l16;
        float bias = b1[col];
#pragma unroll
        for (int i = 0; i < 4; i++) {
#pragma unroll
            for (int r = 0; r < 4; r++) {
                int grow = mtile * 128 + mq * 64 + i * 16 + quad * 4 + r;
                float v = fmaxf(s * acc[i][j][r] + bias, 0.0f);
                lmax = fmaxf(lmax, v);
                if (grow < NN) g_h[(size_t)grow * HID + col] = v;
            }
        }
    }
#pragma unroll
    for (int off = 32; off > 0; off >>= 1) lmax = fmaxf(lmax, __shfl_xor(lmax, off, 64));
    if (lane == 0) atomicMax(&g_amax_bits[3], __float_as_uint(lmax));
}

// ---------------- GEMM2 fused: z = fq(h) @ qw2^T * s + b2 ----------------
// whole qw2 (48x256 bf16 = 24KB) resident in LDS; A: h fp32 -> quant on the fly
__launch_bounds__(256)
__global__ void gemm2_kernel(const float* __restrict__ b2) {
    __shared__ bf16_t lB2[OCP * HID];  // 24 KB
    __shared__ bf16_t lA2[128 * 64];   // 16 KB
    int t = threadIdx.x;
    int mtile = blockIdx.x;
    int lane = t & 63, wv = t >> 6;
    int quad = lane >> 4, l16 = lane & 15;

    // load all of qw2 once: 24576 B = 6 passes x 4KB
#pragma unroll
    for (int p = 0; p < 6; p++)
        GLOAD_LDS16((const char*)g_qw2 + p * 4096 + t * 16,
                    (char*)lB2 + p * 4096 + t * 16);

    float scale_h = __uint_as_float(g_amax_bits[3]) / 127.0f + 1e-12f;
    float rs = 1.0f / scale_h;
    int arow_l = t >> 4;
    int acol   = (t & 15) * 4;

    f32x4 acc[2][3] = {};
#pragma unroll 1
    for (int kit = 0; kit < 4; kit++) {
        __syncthreads();
#pragma unroll
        for (int p = 0; p < 8; p++) {
            int row = p * 16 + arow_l;
            int gr = mtile * 128 + row; if (gr >= NN) gr = NN - 1;
            f32x4 v = *(const f32x4*)(g_h + (size_t)gr * HID + kit * 64 + acol);
            bf16x4 o;
            o[0] = (bf16_t)fminf(fmaxf(rintf(v.x * rs), -128.0f), 127.0f);
            o[1] = (bf16_t)fminf(fmaxf(rintf(v.y * rs), -128.0f), 127.0f);
            o[2] = (bf16_t)fminf(fmaxf(rintf(v.z * rs), -128.0f), 127.0f);
            o[3] = (bf16_t)fminf(fmaxf(rintf(v.w * rs), -128.0f), 127.0f);
            *(bf16x4*)(lA2 + row * 64 + acol) = o;
        }
        __syncthreads();
#pragma unroll
        for (int k32 = 0; k32 < 2; k32++) {
            bf16x8 a[2], b[3];
#pragma unroll
            for (int i = 0; i < 2; i++)
                a[i] = *(const bf16x8*)(lA2 + (wv * 32 + i * 16 + l16) * 64 + k32 * 32 + quad * 8);
#pragma unroll
            for (int j = 0; j < 3; j++)
                b[j] = *(const bf16x8*)(lB2 + (j * 16 + l16) * HID + kit * 64 + k32 * 32 + quad * 8);
#pragma unroll
            for (int i = 0; i < 2; i++)
#pragma unroll
                for (int j = 0; j < 3; j++)
                    acc[i][j] = __builtin_amdgcn_mfma_f32_16x16x32_bf16(a[i], b[j], acc[i][j], 0, 0, 0);
        }
    }
    float s = scale_h * (__uint_as_float(g_amax_bits[2]) / 127.0f + 1e-12f);
#pragma unroll
    for (int j = 0; j < 3; j++) {
        int col = j * 16 + l16;
        float bias = (col < OC) ? b2[col] : 0.0f;
#pragma unroll
        for (int i = 0; i < 2; i++) {
#pragma unroll
            for (int r = 0; r < 4; r++) {
                int grow = mtile * 128 + wv * 32 + i * 16 + quad * 4 + r;
                if (col < OC && grow < NN)
                    g_z[(size_t)grow * OC + col] = s * acc[i][j][r] + bias;
            }
        }
    }
}

// ---------------- degree histogram ----------------
__global__ void deg_kernel(const int* __restrict__ ei) {
    const int* dst = ei + NE;
    int idx = blockIdx.x * blockDim.x + threadIdx.x;
    int stride = gridDim.x * blockDim.x;
    for (int e = idx; e < NE; e += stride) atomicAdd(&g_deg[dst[e]], 1u);
}

__global__ void dinv_kernel() {
    int idx = blockIdx.x * blockDim.x + threadIdx.x;
    int stride = gridDim.x * blockDim.x;
    for (int i = idx; i < NN; i += stride) {
        unsigned d = g_deg[i];
        g_dinv[i] = d ? rsqrtf((float)d) : 0.0f;
    }
}

// ---------------- scan phase 1 ----------------
__global__ void scan1_kernel() {
    int blk = blockIdx.x, t = threadIdx.x;
    int base = blk * SCAN_TILE + t * 4;
    unsigned v[4]; unsigned s = 0;
#pragma unroll
    for (int j = 0; j < 4; j++) { int i = base + j; v[j] = (i < NN) ? g_deg[i] : 0u; s += v[j]; }
    int lane = t & 63, wv = t >> 6;
    unsigned sc = s;
#pragma unroll
    for (int off = 1; off < 64; off <<= 1) {
        unsigned n = __shfl_up(sc, off, 64);
        if (lane >= off) sc += n;
    }
    __shared__ unsigned wsum[4];
    if (lane == 63) wsum[wv] = sc;
    __syncthreads();
    unsigned woff = 0;
    for (int w = 0; w < 4; w++) if (w < wv) woff += wsum[w];
    unsigned run = woff + sc - s;
#pragma unroll
    for (int j = 0; j < 4; j++) { int i = base + j; if (i < NN) g_rowtmp[i] = run; run += v[j]; }
    if (t == 255) g_bsum[blk] = woff + sc;
}

// ---------------- scan phase 2 ----------------
__global__ void scan2_kernel() {
    int t = threadIdx.x;
    unsigned v = (t < SCAN_NB) ? g_bsum[t] : 0u;
    int lane = t & 63, wv = t >> 6;
    unsigned sc = v;
#pragma unroll
    for (int off = 1; off < 64; off <<= 1) {
        unsigned n = __shfl_up(sc, off, 64);
        if (lane >= off) sc += n;
    }
    __shared__ unsigned ws[2];
    if (lane == 63) ws[wv] = sc;
    __syncthreads();
    unsigned excl = sc - v + (wv ? ws[0] : 0u);
    if (t < SCAN_NB) g_boff[t] = excl;
}

// ---------------- scan phase 3 ----------------
__global__ void scan3_kernel() {
    int i = blockIdx.x * blockDim.x + threadIdx.x;
    if (i < NN) {
        unsigned r = g_rowtmp[i] + g_boff[i / SCAN_TILE];
        g_rowstart[i] = r;
        g_cursor[i] = r;
    }
    if (i == 0) g_rowstart[NN] = NE;
}

// ---------------- CSR bucket fill ----------------
__global__ void fill_kernel(const int* __restrict__ ei) {
    const int* srcp = ei;
    const int* dstp = ei + NE;
    int idx = blockIdx.x * blockDim.x + threadIdx.x;
    int stride = gridDim.x * blockDim.x;
    for (int e = idx; e < NE; e += stride) {
        int d = dstp[e];
        unsigned pos = atomicAdd(&g_cursor[d], 1u);
        g_csr_src[pos] = srcp[e];
    }
}

// ---------------- gather + fused log_softmax: one wave per node ----------------
__launch_bounds__(256)
__global__ void gather_kernel(float* __restrict__ out) {
    int node = (blockIdx.x * 256 + threadIdx.x) >> 6;
    int lane = threadIdx.x & 63;
    if (node >= NN) return;
    unsigned e0 = g_rowstart[node], e1 = g_rowstart[node + 1];
    float dinvd = g_dinv[node];
    float acc = 0.0f;
    unsigned e = e0;
    for (; e + 2 <= e1; e += 2) {
        int s0 = g_csr_src[e], s1 = g_csr_src[e + 1];
        float c0 = g_dinv[s0] * dinvd;
        float c1 = g_dinv[s1] * dinvd;
        float z0 = (lane < OC) ? g_z[(size_t)s0 * OC + lane] : 0.0f;
        float z1 = (lane < OC) ? g_z[(size_t)s1 * OC + lane] : 0.0f;
        acc += z0 * c0 + z1 * c1;
    }
    if (e < e1) {
        int s0 = g_csr_src[e];
        float c0 = g_dinv[s0] * dinvd;
        float z0 = (lane < OC) ? g_z[(size_t)s0 * OC + lane] : 0.0f;
        acc += z0 * c0;
    }
    float m = (lane < OC) ? acc : -1e30f;
#pragma unroll
    for (int off = 32; off > 0; off >>= 1) m = fmaxf(m, __shfl_xor(m, off, 64));
    float ex = (lane < OC) ? __expf(acc - m) : 0.0f;
    float ssum = ex;
#pragma unroll
    for (int off = 32; off > 0; off >>= 1) ssum += __shfl_xor(ssum, off, 64);
    float lg = __logf(ssum);
    if (lane < OC) out[(size_t)node * OC + lane] = acc - m - lg;
}

extern "C" void kernel_launch(void* const* d_in, const int* in_sizes, int n_in,
                              void* d_out, int out_size, void* d_ws, size_t ws_size,
                              hipStream_t stream) {
    const float* x  = (const float*)d_in[0];
    const int*   ei = (const int*)d_in[1];
    const float* w1 = (const float*)d_in[2];
    const float* b1 = (const float*)d_in[3];
    const float* w2 = (const float*)d_in[4];
    const float* b2 = (const float*)d_in[5];
    float* out = (float*)d_out;
    (void)d_ws; (void)ws_size; (void)in_sizes; (void)n_in; (void)out_size;

    init_kernel<<<1024, 256, 0, stream>>>();
    // topology pipeline
    deg_kernel<<<2048, 256, 0, stream>>>(ei);
    dinv_kernel<<<391, 256, 0, stream>>>();
    scan1_kernel<<<SCAN_NB, 256, 0, stream>>>();
    scan2_kernel<<<1, 128, 0, stream>>>();
    scan3_kernel<<<391, 256, 0, stream>>>();
    fill_kernel<<<2048, 256, 0, stream>>>(ei);
    // feature pipeline
    absmax_kernel<<<2048, 256, 0, stream>>>(x,  (NN * INC) / 4, 0);
    absmax_kernel<<<128, 256, 0, stream>>>(w1, (HID * INC) / 4, 1);
    absmax_kernel<<<10, 256, 0, stream>>>(w2,  (OC * HID) / 4, 2);
    quantw_kernel<<<128, 256, 0, stream>>>(w1, (HID * INC) / 4, 1, 0);
    quantw_kernel<<<10, 256, 0, stream>>>(w2,  (OC * HID) / 4, 2, 1);
    gemm1_kernel<<<((NN + 127) / 128) * 2, 256, 0, stream>>>(x, b1);
    gemm2_kernel<<<(NN + 127) / 128, 256, 0, stream>>>(b2);
    gather_kernel<<<(NN + 3) / 4, 256, 0, stream>>>(out);
}

// Round 5
// 765.303 us; speedup vs baseline: 5.3059x; 1.0208x over previous
//
#include <hip/hip_runtime.h>
#include <hip/hip_bf16.h>
#include <stdint.h>
#include <stddef.h>

#define NN   100000   // nodes
#define NE   1600000  // edges
#define INC  512      // in channels
#define HID  256      // hidden
#define OC   40       // out channels
#define OCP  48       // padded out channels (3 x 16 col-tiles)

#define LDK  72       // padded LDS row stride (64 + 8): bank-conflict-free
#define LDB2 264      // padded lB2 row stride (256 + 8)

#define SCAN_TILE 1024
#define SCAN_NB  ((NN + SCAN_TILE - 1) / SCAN_TILE)   // 98

typedef __bf16 bf16_t;
typedef __bf16 bf16x8 __attribute__((ext_vector_type(8)));
typedef __bf16 bf16x4 __attribute__((ext_vector_type(4)));
typedef float  f32x4  __attribute__((ext_vector_type(4)));

// ---- device-global scratch ----
__device__ unsigned g_amax_bits[4];          // 0:x 1:w1 2:w2 3:h
__device__ unsigned g_deg[NN];
__device__ float    g_dinv[NN];
__device__ bf16_t   g_qw1[HID * INC];
__device__ bf16_t   g_qw2[OCP * HID];        // rows 40..47 zero
__device__ float    g_h[(size_t)NN * HID];   // relu(fc1) fp32
__device__ float    g_z[(size_t)NN * OC];    // fc2 output (16 MB -> L2/L3 resident)
// CSR-by-destination
__device__ unsigned g_rowtmp[NN];
__device__ unsigned g_rowstart[NN + 1];
__device__ unsigned g_cursor[NN];
__device__ unsigned g_bsum[SCAN_NB];
__device__ unsigned g_boff[SCAN_NB];
__device__ int      g_csr_src[NE];

__device__ __forceinline__ bf16_t quant1(float v, float rs) {
    return (bf16_t)fminf(fmaxf(rintf(v * rs), -128.0f), 127.0f);
}

// ---------------- init ----------------
__global__ void init_kernel() {
    int idx = blockIdx.x * blockDim.x + threadIdx.x;
    int stride = gridDim.x * blockDim.x;
    for (int i = idx; i < NN; i += stride) g_deg[i] = 0u;
    for (int i = idx; i < OCP * HID; i += stride) g_qw2[i] = (bf16_t)0.0f;
    if (idx < 4) g_amax_bits[idx] = 0u;
}

// ---------------- absmax reduction ----------------
__global__ void absmax_kernel(const float* __restrict__ src, int n4, int slot) {
    int idx = blockIdx.x * blockDim.x + threadIdx.x;
    int stride = gridDim.x * blockDim.x;
    const f32x4* s4 = (const f32x4*)src;
    float m = 0.0f;
    for (int i = idx; i < n4; i += stride) {
        f32x4 v = s4[i];
        m = fmaxf(m, fmaxf(fmaxf(fabsf(v.x), fabsf(v.y)),
                           fmaxf(fabsf(v.z), fabsf(v.w))));
    }
#pragma unroll
    for (int off = 32; off > 0; off >>= 1) m = fmaxf(m, __shfl_xor(m, off, 64));
    __shared__ float sm[4];
    if ((threadIdx.x & 63) == 0) sm[threadIdx.x >> 6] = m;
    __syncthreads();
    if (threadIdx.x == 0) {
        float mm = fmaxf(fmaxf(sm[0], sm[1]), fmaxf(sm[2], sm[3]));
        atomicMax(&g_amax_bits[slot], __float_as_uint(mm));
    }
}

// ------------- quantize weights to bf16-exact ints -------------
__global__ void quantw_kernel(const float* __restrict__ src, int n4, int slot, int which) {
    bf16_t* dst = which ? g_qw2 : g_qw1;
    float rs = 1.0f / (__uint_as_float(g_amax_bits[slot]) / 127.0f + 1e-12f);
    int idx = blockIdx.x * blockDim.x + threadIdx.x;
    int stride = gridDim.x * blockDim.x;
    const f32x4* s4 = (const f32x4*)src;
    bf16x4* d4 = (bf16x4*)dst;
    for (int i = idx; i < n4; i += stride) {
        f32x4 v = s4[i];
        bf16x4 o;
        o[0] = quant1(v.x, rs); o[1] = quant1(v.y, rs);
        o[2] = quant1(v.z, rs); o[3] = quant1(v.w, rs);
        d4[i] = o;
    }
}

// ---------------- GEMM1 fused: h = relu(fq(x) @ qw1^T * s + b1), amax(h) ----------------
// 128x128 tile, BK=64, padded LDS stride 72 (conflict-free), R3 barrier structure.
__launch_bounds__(256)
__global__ void gemm1_kernel(const float* __restrict__ x, const float* __restrict__ b1) {
    __shared__ bf16_t lA[128 * LDK];
    __shared__ bf16_t lB[128 * LDK];
    int t = threadIdx.x;
    int mtile = blockIdx.x >> 1, ntile = blockIdx.x & 1;
    int lane = t & 63, wv = t >> 6;
    int quad = lane >> 4, l16 = lane & 15;
    int mq = wv >> 1, nq = wv & 1;

    float scale_x = __uint_as_float(g_amax_bits[0]) / 127.0f + 1e-12f;
    float rs = 1.0f / scale_x;

    int srow = t >> 3;     // 0..31
    int sch  = t & 7;      // 16B chunk 0..7

    const float*  xbase[4];
    const bf16_t* wbase[4];
#pragma unroll
    for (int p = 0; p < 4; p++) {
        int gr = mtile * 128 + p * 32 + srow; if (gr >= NN) gr = NN - 1;
        xbase[p] = x + (size_t)gr * INC + sch * 8;
        wbase[p] = g_qw1 + (size_t)(ntile * 128 + p * 32 + srow) * INC + sch * 8;
    }

    f32x4 acc[4][4] = {};
#pragma unroll 1
    for (int kit = 0; kit < 8; kit++) {
        __syncthreads();
#pragma unroll
        for (int p = 0; p < 4; p++) {
            int row = p * 32 + srow;
            f32x4 v0 = *(const f32x4*)(xbase[p] + kit * 64);
            f32x4 v1 = *(const f32x4*)(xbase[p] + kit * 64 + 4);
            bf16x8 bb = *(const bf16x8*)(wbase[p] + kit * 64);
            bf16x8 o;
            o[0] = quant1(v0.x, rs); o[1] = quant1(v0.y, rs);
            o[2] = quant1(v0.z, rs); o[3] = quant1(v0.w, rs);
            o[4] = quant1(v1.x, rs); o[5] = quant1(v1.y, rs);
            o[6] = quant1(v1.z, rs); o[7] = quant1(v1.w, rs);
            *(bf16x8*)(lA + row * LDK + sch * 8) = o;
            *(bf16x8*)(lB + row * LDK + sch * 8) = bb;
        }
        __syncthreads();
#pragma unroll
        for (int k32 = 0; k32 < 2; k32++) {
            int cs = (k32 * 4 + quad) * 8;
            bf16x8 a[4], b[4];
#pragma unroll
            for (int i = 0; i < 4; i++)
                a[i] = *(const bf16x8*)(lA + (mq * 64 + i * 16 + l16) * LDK + cs);
#pragma unroll
            for (int j = 0; j < 4; j++)
                b[j] = *(const bf16x8*)(lB + (nq * 64 + j * 16 + l16) * LDK + cs);
#pragma unroll
            for (int i = 0; i < 4; i++)
#pragma unroll
                for (int j = 0; j < 4; j++)
                    acc[i][j] = __builtin_amdgcn_mfma_f32_16x16x32_bf16(a[i], b[j], acc[i][j], 0, 0, 0);
        }
    }
    float s = scale_x * (__uint_as_float(g_amax_bits[1]) / 127.0f + 1e-12f);
    float lmax = 0.0f;
#pragma unroll
    for (int j = 0; j < 4; j++) {
        int col = ntile * 128 + nq * 64 + j * 16 + l16;
        float bias = b1[col];
#pragma unroll
        for (int i = 0; i < 4; i++) {
#pragma unroll
            for (int r = 0; r < 4; r++) {
                int grow = mtile * 128 + mq * 64 + i * 16 + quad * 4 + r;
                float v = fmaxf(s * acc[i][j][r] + bias, 0.0f);
                lmax = fmaxf(lmax, v);
                if (grow < NN) g_h[(size_t)grow * HID + col] = v;
            }
        }
    }
#pragma unroll
    for (int off = 32; off > 0; off >>= 1) lmax = fmaxf(lmax, __shfl_xor(lmax, off, 64));
    if (lane == 0) atomicMax(&g_amax_bits[3], __float_as_uint(lmax));
}

// ---------------- GEMM2 fused: z = fq(h) @ qw2^T * s + b2 ----------------
// qw2 resident in LDS (padded stride 264); A staged fp32->quant, padded stride 72.
__launch_bounds__(256)
__global__ void gemm2_kernel(const float* __restrict__ b2) {
    __shared__ bf16_t lB2[OCP * LDB2];
    __shared__ bf16_t lA2[128 * LDK];
    int t = threadIdx.x;
    int mtile = blockIdx.x;
    int lane = t & 63, wv = t >> 6;
    int quad = lane >> 4, l16 = lane & 15;

#pragma unroll
    for (int p = 0; p < 6; p++) {
        int ci = p * 256 + t;             // 0..1535 chunks of 8 elements
        int row = ci >> 5, ch = ci & 31;
        *(bf16x8*)(lB2 + row * LDB2 + ch * 8) =
            *(const bf16x8*)(g_qw2 + row * 256 + ch * 8);
    }

    float scale_h = __uint_as_float(g_amax_bits[3]) / 127.0f + 1e-12f;
    float rs = 1.0f / scale_h;
    int srow = t >> 3, sch = t & 7;
    const float* hbase[4];
#pragma unroll
    for (int p = 0; p < 4; p++) {
        int gr = mtile * 128 + p * 32 + srow; if (gr >= NN) gr = NN - 1;
        hbase[p] = g_h + (size_t)gr * HID + sch * 8;
    }

    f32x4 acc[2][3] = {};
#pragma unroll 1
    for (int kit = 0; kit < 4; kit++) {
        if (kit) __syncthreads();
#pragma unroll
        for (int p = 0; p < 4; p++) {
            int row = p * 32 + srow;
            f32x4 v0 = *(const f32x4*)(hbase[p] + kit * 64);
            f32x4 v1 = *(const f32x4*)(hbase[p] + kit * 64 + 4);
            bf16x8 o;
            o[0] = quant1(v0.x, rs); o[1] = quant1(v0.y, rs);
            o[2] = quant1(v0.z, rs); o[3] = quant1(v0.w, rs);
            o[4] = quant1(v1.x, rs); o[5] = quant1(v1.y, rs);
            o[6] = quant1(v1.z, rs); o[7] = quant1(v1.w, rs);
            *(bf16x8*)(lA2 + row * LDK + sch * 8) = o;
        }
        __syncthreads();   // also orders the one-time lB2 fill before first use
#pragma unroll
        for (int k32 = 0; k32 < 2; k32++) {
            int csA = (k32 * 4 + quad) * 8;
            int chB = (kit * 8 + k32 * 4 + quad) * 8;
            bf16x8 a[2], b[3];
#pragma unroll
            for (int i = 0; i < 2; i++)
                a[i] = *(const bf16x8*)(lA2 + (wv * 32 + i * 16 + l16) * LDK + csA);
#pragma unroll
            for (int j = 0; j < 3; j++)
                b[j] = *(const bf16x8*)(lB2 + (j * 16 + l16) * LDB2 + chB);
#pragma unroll
            for (int i = 0; i < 2; i++)
#pragma unroll
                for (int j = 0; j < 3; j++)
                    acc[i][j] = __builtin_amdgcn_mfma_f32_16x16x32_bf16(a[i], b[j], acc[i][j], 0, 0, 0);
        }
    }
    float s = scale_h * (__uint_as_float(g_amax_bits[2]) / 127.0f + 1e-12f);
#pragma unroll
    for (int j = 0; j < 3; j++) {
        int col = j * 16 + l16;
        float bias = (col < OC) ? b2[col] : 0.0f;
#pragma unroll
        for (int i = 0; i < 2; i++) {
#pragma unroll
            for (int r = 0; r < 4; r++) {
                int grow = mtile * 128 + wv * 32 + i * 16 + quad * 4 + r;
                if (col < OC && grow < NN)
                    g_z[(size_t)grow * OC + col] = s * acc[i][j][r] + bias;
            }
        }
    }
}

// ---------------- degree histogram ----------------
__global__ void deg_kernel(const int* __restrict__ ei) {
    const int* dst = ei + NE;
    int idx = blockIdx.x * blockDim.x + threadIdx.x;
    int stride = gridDim.x * blockDim.x;
    for (int e = idx; e < NE; e += stride) atomicAdd(&g_deg[dst[e]], 1u);
}

// ---------------- scan phase 1 (+ dinv fused) ----------------
__global__ void scan1_kernel() {
    int blk = blockIdx.x, t = threadIdx.x;
    int base = blk * SCAN_TILE + t * 4;
    unsigned v[4]; unsigned s = 0;
#pragma unroll
    for (int j = 0; j < 4; j++) {
        int i = base + j;
        v[j] = (i < NN) ? g_deg[i] : 0u;
        s += v[j];
        if (i < NN) g_dinv[i] = v[j] ? rsqrtf((float)v[j]) : 0.0f;
    }
    int lane = t & 63, wv = t >> 6;
    unsigned sc = s;
#pragma unroll
    for (int off = 1; off < 64; off <<= 1) {
        unsigned n = __shfl_up(sc, off, 64);
        if (lane >= off) sc += n;
    }
    __shared__ unsigned wsum[4];
    if (lane == 63) wsum[wv] = sc;
    __syncthreads();
    unsigned woff = 0;
    for (int w = 0; w < 4; w++) if (w < wv) woff += wsum[w];
    unsigned run = woff + sc - s;
#pragma unroll
    for (int j = 0; j < 4; j++) { int i = base + j; if (i < NN) g_rowtmp[i] = run; run += v[j]; }
    if (t == 255) g_bsum[blk] = woff + sc;
}

// ---------------- scan phase 2 ----------------
__global__ void scan2_kernel() {
    int t = threadIdx.x;
    unsigned v = (t < SCAN_NB) ? g_bsum[t] : 0u;
    int lane = t & 63, wv = t >> 6;
    unsigned sc = v;
#pragma unroll
    for (int off = 1; off < 64; off <<= 1) {
        unsigned n = __shfl_up(sc, off, 64);
        if (lane >= off) sc += n;
    }
    __shared__ unsigned ws[2];
    if (lane == 63) ws[wv] = sc;
    __syncthreads();
    unsigned excl = sc - v + (wv ? ws[0] : 0u);
    if (t < SCAN_NB) g_boff[t] = excl;
}

// ---------------- scan phase 3 ----------------
__global__ void scan3_kernel() {
    int i = blockIdx.x * blockDim.x + threadIdx.x;
    if (i < NN) {
        unsigned r = g_rowtmp[i] + g_boff[i / SCAN_TILE];
        g_rowstart[i] = r;
        g_cursor[i] = r;
    }
    if (i == 0) g_rowstart[NN] = NE;
}

// ---------------- CSR bucket fill ----------------
__global__ void fill_kernel(const int* __restrict__ ei) {
    const int* srcp = ei;
    const int* dstp = ei + NE;
    int idx = blockIdx.x * blockDim.x + threadIdx.x;
    int stride = gridDim.x * blockDim.x;
    for (int e = idx; e < NE; e += stride) {
        int d = dstp[e];
        unsigned pos = atomicAdd(&g_cursor[d], 1u);
        g_csr_src[pos] = srcp[e];
    }
}

// ---------------- gather + fused log_softmax: one wave per node ----------------
__launch_bounds__(256)
__global__ void gather_kernel(float* __restrict__ out) {
    int node = (blockIdx.x * 256 + threadIdx.x) >> 6;
    int lane = threadIdx.x & 63;
    if (node >= NN) return;
    unsigned e0 = g_rowstart[node], e1 = g_rowstart[node + 1];
    float dinvd = g_dinv[node];
    float acc = 0.0f;
    unsigned e = e0;
    for (; e + 2 <= e1; e += 2) {
        int s0 = g_csr_src[e], s1 = g_csr_src[e + 1];
        float c0 = g_dinv[s0] * dinvd;
        float c1 = g_dinv[s1] * dinvd;
        float z0 = (lane < OC) ? g_z[(size_t)s0 * OC + lane] : 0.0f;
        float z1 = (lane < OC) ? g_z[(size_t)s1 * OC + lane] : 0.0f;
        acc += z0 * c0 + z1 * c1;
    }
    if (e < e1) {
        int s0 = g_csr_src[e];
        float c0 = g_dinv[s0] * dinvd;
        float z0 = (lane < OC) ? g_z[(size_t)s0 * OC + lane] : 0.0f;
        acc += z0 * c0;
    }
    float m = (lane < OC) ? acc : -1e30f;
#pragma unroll
    for (int off = 32; off > 0; off >>= 1) m = fmaxf(m, __shfl_xor(m, off, 64));
    float ex = (lane < OC) ? __expf(acc - m) : 0.0f;
    float ssum = ex;
#pragma unroll
    for (int off = 32; off > 0; off >>= 1) ssum += __shfl_xor(ssum, off, 64);
    float lg = __logf(ssum);
    if (lane < OC) out[(size_t)node * OC + lane] = acc - m - lg;
}

extern "C" void kernel_launch(void* const* d_in, const int* in_sizes, int n_in,
                              void* d_out, int out_size, void* d_ws, size_t ws_size,
                              hipStream_t stream) {
    const float* x  = (const float*)d_in[0];
    const int*   ei = (const int*)d_in[1];
    const float* w1 = (const float*)d_in[2];
    const float* b1 = (const float*)d_in[3];
    const float* w2 = (const float*)d_in[4];
    const float* b2 = (const float*)d_in[5];
    float* out = (float*)d_out;
    (void)d_ws; (void)ws_size; (void)in_sizes; (void)n_in; (void)out_size;

    init_kernel<<<1024, 256, 0, stream>>>();
    // topology pipeline
    deg_kernel<<<2048, 256, 0, stream>>>(ei);
    scan1_kernel<<<SCAN_NB, 256, 0, stream>>>();
    scan2_kernel<<<1, 128, 0, stream>>>();
    scan3_kernel<<<391, 256, 0, stream>>>();
    fill_kernel<<<2048, 256, 0, stream>>>(ei);
    // feature pipeline
    absmax_kernel<<<2048, 256, 0, stream>>>(x,  (NN * INC) / 4, 0);
    absmax_kernel<<<128, 256, 0, stream>>>(w1, (HID * INC) / 4, 1);
    absmax_kernel<<<10, 256, 0, stream>>>(w2,  (OC * HID) / 4, 2);
    quantw_kernel<<<128, 256, 0, stream>>>(w1, (HID * INC) / 4, 1, 0);
    quantw_kernel<<<10, 256, 0, stream>>>(w2,  (OC * HID) / 4, 2, 1);
    gemm1_kernel<<<((NN + 127) / 128) * 2, 256, 0, stream>>>(x, b1);
    gemm2_kernel<<<(NN + 127) / 128, 256, 0, stream>>>(b2);
    gather_kernel<<<(NN + 3) / 4, 256, 0, stream>>>(out);
}

// Round 6
// 642.510 us; speedup vs baseline: 6.3199x; 1.1911x over previous
//
#include <hip/hip_runtime.h>
#include <hip/hip_bf16.h>
#include <stdint.h>
#include <stddef.h>

#define NN   100000   // nodes
#define NE   1600000  // edges
#define INC  512      // in channels
#define HID  256      // hidden
#define OC   40       // out channels
#define OCP  48       // padded out channels (3 x 16 col-tiles)

#define LDK  72       // padded LDS row stride (64 + 8): bank-conflict-free
#define LDB2 264      // padded lB2 row stride (256 + 8)

#define NBKT ((NN + 255) / 256)   // 391 coarse buckets of 256 nodes

typedef __bf16 bf16_t;
typedef __bf16 bf16x8 __attribute__((ext_vector_type(8)));
typedef __bf16 bf16x4 __attribute__((ext_vector_type(4)));
typedef float  f32x4  __attribute__((ext_vector_type(4)));

// ---- device-global scratch ----
__device__ unsigned g_amax_bits[4];          // 0:x 1:w1 2:w2 3:h
__device__ float    g_dinv[NN];
__device__ bf16_t   g_qw1[HID * INC];
__device__ bf16_t   g_qw2[OCP * HID];        // rows 40..47 zero
__device__ float    g_h[(size_t)NN * HID];   // relu(fc1) fp32
__device__ float    g_z[(size_t)NN * OC];    // fc2 output (16 MB -> L2/L3 resident)
// CSR-by-destination (two-level binned build)
__device__ unsigned g_chist[NBKT];
__device__ unsigned g_cstart[NBKT + 1];
__device__ unsigned g_ccur[NBKT];
__device__ uint2    g_bin[NE];               // (src, dst) grouped by coarse bucket
__device__ unsigned g_rowstart[NN + 1];
__device__ int      g_csr_src[NE];

__device__ __forceinline__ bf16_t quant1(float v, float rs) {
    return (bf16_t)fminf(fmaxf(rintf(v * rs), -128.0f), 127.0f);
}

// ---------------- init ----------------
__global__ void init_kernel() {
    int idx = blockIdx.x * blockDim.x + threadIdx.x;
    int stride = gridDim.x * blockDim.x;
    for (int i = idx; i < NBKT; i += stride) g_chist[i] = 0u;
    for (int i = idx; i < OCP * HID; i += stride) g_qw2[i] = (bf16_t)0.0f;
    if (idx < 4) g_amax_bits[idx] = 0u;
}

// ---------------- coarse histogram: 391 buckets, LDS-aggregated ----------------
__global__ void chist_kernel(const int* __restrict__ ei) {
    const int* dst = ei + NE;
    __shared__ unsigned hist[NBKT];
    int t = threadIdx.x;
    for (int i = t; i < NBKT; i += 256) hist[i] = 0u;
    __syncthreads();
    int idx = blockIdx.x * 256 + t;
    int stride = gridDim.x * 256;
    for (int e = idx; e < NE; e += stride) atomicAdd(&hist[dst[e] >> 8], 1u);
    __syncthreads();
    for (int i = t; i < NBKT; i += 256) {
        unsigned c = hist[i];
        if (c) atomicAdd(&g_chist[i], c);
    }
}

// ---------------- coarse scan (1 block, 512 threads = 8 waves) ----------------
__global__ void cscan_kernel() {
    int t = threadIdx.x;
    unsigned v = (t < NBKT) ? g_chist[t] : 0u;
    int lane = t & 63, wv = t >> 6;
    unsigned sc = v;
#pragma unroll
    for (int off = 1; off < 64; off <<= 1) {
        unsigned n = __shfl_up(sc, off, 64);
        if (lane >= off) sc += n;
    }
    __shared__ unsigned ws[8];
    if (lane == 63) ws[wv] = sc;
    __syncthreads();
    unsigned woff = 0;
    for (int w = 0; w < 8; w++) if (w < wv) woff += ws[w];
    unsigned excl = woff + sc - v;
    if (t < NBKT) { g_cstart[t] = excl; g_ccur[t] = excl; }
    if (t == 0) g_cstart[NBKT] = NE;
}

// ---------------- bin: group edges by coarse bucket (block-local LDS sort) ----------------
#define BIN_BLOCKS 200
#define BIN_EPB    (NE / BIN_BLOCKS)   // 8000
__global__ void bin_kernel(const int* __restrict__ ei) {
    const int* srcp = ei;
    const int* dstp = ei + NE;
    __shared__ unsigned hist[NBKT];
    __shared__ unsigned base[NBKT];
    int t = threadIdx.x;
    int e0 = blockIdx.x * BIN_EPB, e1 = e0 + BIN_EPB;
    for (int i = t; i < NBKT; i += 256) hist[i] = 0u;
    __syncthreads();
    for (int e = e0 + t; e < e1; e += 256) atomicAdd(&hist[dstp[e] >> 8], 1u);
    __syncthreads();
    for (int i = t; i < NBKT; i += 256) {
        unsigned c = hist[i];
        base[i] = c ? atomicAdd(&g_ccur[i], c) : 0u;
        hist[i] = 0u;   // reuse as local cursor
    }
    __syncthreads();
    for (int e = e0 + t; e < e1; e += 256) {
        int d = dstp[e], s = srcp[e];
        int b = d >> 8;
        unsigned r = atomicAdd(&hist[b], 1u);
        g_bin[base[b] + r] = make_uint2((unsigned)s, (unsigned)d);
    }
}

// ---------------- local: per-bucket node histogram -> rowstart/dinv/csr_src ----------------
__global__ void local_kernel() {
    int b = blockIdx.x, t = threadIdx.x;
    unsigned e0 = g_cstart[b], e1 = g_cstart[b + 1];
    __shared__ unsigned hist[256];
    __shared__ unsigned curs[256];
    __shared__ unsigned wsum[4];
    hist[t] = 0u;
    __syncthreads();
    for (unsigned e = e0 + t; e < e1; e += 256) atomicAdd(&hist[g_bin[e].y & 255], 1u);
    __syncthreads();
    unsigned v = hist[t];
    int lane = t & 63, wv = t >> 6;
    unsigned sc = v;
#pragma unroll
    for (int off = 1; off < 64; off <<= 1) {
        unsigned n = __shfl_up(sc, off, 64);
        if (lane >= off) sc += n;
    }
    if (lane == 63) wsum[wv] = sc;
    __syncthreads();
    unsigned woff = 0;
    for (int w = 0; w < 4; w++) if (w < wv) woff += wsum[w];
    unsigned excl = woff + sc - v;
    int node = b * 256 + t;
    if (node < NN) {
        g_rowstart[node] = e0 + excl;
        g_dinv[node] = v ? rsqrtf((float)v) : 0.0f;
    }
    if (b == 0 && t == 0) g_rowstart[NN] = NE;
    curs[t] = excl;
    __syncthreads();
    for (unsigned e = e0 + t; e < e1; e += 256) {
        uint2 ed = g_bin[e];
        unsigned r = atomicAdd(&curs[ed.y & 255], 1u);
        g_csr_src[e0 + r] = (int)ed.x;
    }
}

// ---------------- absmax reduction ----------------
__global__ void absmax_kernel(const float* __restrict__ src, int n4, int slot) {
    int idx = blockIdx.x * blockDim.x + threadIdx.x;
    int stride = gridDim.x * blockDim.x;
    const f32x4* s4 = (const f32x4*)src;
    float m = 0.0f;
    for (int i = idx; i < n4; i += stride) {
        f32x4 v = s4[i];
        m = fmaxf(m, fmaxf(fmaxf(fabsf(v.x), fabsf(v.y)),
                           fmaxf(fabsf(v.z), fabsf(v.w))));
    }
#pragma unroll
    for (int off = 32; off > 0; off >>= 1) m = fmaxf(m, __shfl_xor(m, off, 64));
    __shared__ float sm[4];
    if ((threadIdx.x & 63) == 0) sm[threadIdx.x >> 6] = m;
    __syncthreads();
    if (threadIdx.x == 0) {
        float mm = fmaxf(fmaxf(sm[0], sm[1]), fmaxf(sm[2], sm[3]));
        atomicMax(&g_amax_bits[slot], __float_as_uint(mm));
    }
}

// ------------- quantize weights to bf16-exact ints -------------
__global__ void quantw_kernel(const float* __restrict__ src, int n4, int slot, int which) {
    bf16_t* dst = which ? g_qw2 : g_qw1;
    float rs = 1.0f / (__uint_as_float(g_amax_bits[slot]) / 127.0f + 1e-12f);
    int idx = blockIdx.x * blockDim.x + threadIdx.x;
    int stride = gridDim.x * blockDim.x;
    const f32x4* s4 = (const f32x4*)src;
    bf16x4* d4 = (bf16x4*)dst;
    for (int i = idx; i < n4; i += stride) {
        f32x4 v = s4[i];
        bf16x4 o;
        o[0] = quant1(v.x, rs); o[1] = quant1(v.y, rs);
        o[2] = quant1(v.z, rs); o[3] = quant1(v.w, rs);
        d4[i] = o;
    }
}

// ---------------- GEMM1 fused: h = relu(fq(x) @ qw1^T * s + b1), amax(h) ----------------
__launch_bounds__(256)
__global__ void gemm1_kernel(const float* __restrict__ x, const float* __restrict__ b1) {
    __shared__ bf16_t lA[128 * LDK];
    __shared__ bf16_t lB[128 * LDK];
    int t = threadIdx.x;
    int mtile = blockIdx.x >> 1, ntile = blockIdx.x & 1;
    int lane = t & 63, wv = t >> 6;
    int quad = lane >> 4, l16 = lane & 15;
    int mq = wv >> 1, nq = wv & 1;

    float scale_x = __uint_as_float(g_amax_bits[0]) / 127.0f + 1e-12f;
    float rs = 1.0f / scale_x;

    int srow = t >> 3;     // 0..31
    int sch  = t & 7;      // 16B chunk 0..7

    const float*  xbase[4];
    const bf16_t* wbase[4];
#pragma unroll
    for (int p = 0; p < 4; p++) {
        int gr = mtile * 128 + p * 32 + srow; if (gr >= NN) gr = NN - 1;
        xbase[p] = x + (size_t)gr * INC + sch * 8;
        wbase[p] = g_qw1 + (size_t)(ntile * 128 + p * 32 + srow) * INC + sch * 8;
    }

    f32x4 acc[4][4] = {};
#pragma unroll 1
    for (int kit = 0; kit < 8; kit++) {
        __syncthreads();
#pragma unroll
        for (int p = 0; p < 4; p++) {
            int row = p * 32 + srow;
            f32x4 v0 = *(const f32x4*)(xbase[p] + kit * 64);
            f32x4 v1 = *(const f32x4*)(xbase[p] + kit * 64 + 4);
            bf16x8 bb = *(const bf16x8*)(wbase[p] + kit * 64);
            bf16x8 o;
            o[0] = quant1(v0.x, rs); o[1] = quant1(v0.y, rs);
            o[2] = quant1(v0.z, rs); o[3] = quant1(v0.w, rs);
            o[4] = quant1(v1.x, rs); o[5] = quant1(v1.y, rs);
            o[6] = quant1(v1.z, rs); o[7] = quant1(v1.w, rs);
            *(bf16x8*)(lA + row * LDK + sch * 8) = o;
            *(bf16x8*)(lB + row * LDK + sch * 8) = bb;
        }
        __syncthreads();
#pragma unroll
        for (int k32 = 0; k32 < 2; k32++) {
            int cs = (k32 * 4 + quad) * 8;
            bf16x8 a[4], b[4];
#pragma unroll
            for (int i = 0; i < 4; i++)
                a[i] = *(const bf16x8*)(lA + (mq * 64 + i * 16 + l16) * LDK + cs);
#pragma unroll
            for (int j = 0; j < 4; j++)
                b[j] = *(const bf16x8*)(lB + (nq * 64 + j * 16 + l16) * LDK + cs);
#pragma unroll
            for (int i = 0; i < 4; i++)
#pragma unroll
                for (int j = 0; j < 4; j++)
                    acc[i][j] = __builtin_amdgcn_mfma_f32_16x16x32_bf16(a[i], b[j], acc[i][j], 0, 0, 0);
        }
    }
    float s = scale_x * (__uint_as_float(g_amax_bits[1]) / 127.0f + 1e-12f);
    float lmax = 0.0f;
#pragma unroll
    for (int j = 0; j < 4; j++) {
        int col = ntile * 128 + nq * 64 + j * 16 + l16;
        float bias = b1[col];
#pragma unroll
        for (int i = 0; i < 4; i++) {
#pragma unroll
            for (int r = 0; r < 4; r++) {
                int grow = mtile * 128 + mq * 64 + i * 16 + quad * 4 + r;
                float v = fmaxf(s * acc[i][j][r] + bias, 0.0f);
                lmax = fmaxf(lmax, v);
                if (grow < NN) g_h[(size_t)grow * HID + col] = v;
            }
        }
    }
#pragma unroll
    for (int off = 32; off > 0; off >>= 1) lmax = fmaxf(lmax, __shfl_xor(lmax, off, 64));
    if (lane == 0) atomicMax(&g_amax_bits[3], __float_as_uint(lmax));
}

// ---------------- GEMM2 fused: z = fq(h) @ qw2^T * s + b2 ----------------
__launch_bounds__(256)
__global__ void gemm2_kernel(const float* __restrict__ b2) {
    __shared__ bf16_t lB2[OCP * LDB2];
    __shared__ bf16_t lA2[128 * LDK];
    int t = threadIdx.x;
    int mtile = blockIdx.x;
    int lane = t & 63, wv = t >> 6;
    int quad = lane >> 4, l16 = lane & 15;

#pragma unroll
    for (int p = 0; p < 6; p++) {
        int ci = p * 256 + t;             // 0..1535 chunks of 8 elements
        int row = ci >> 5, ch = ci & 31;
        *(bf16x8*)(lB2 + row * LDB2 + ch * 8) =
            *(const bf16x8*)(g_qw2 + row * 256 + ch * 8);
    }

    float scale_h = __uint_as_float(g_amax_bits[3]) / 127.0f + 1e-12f;
    float rs = 1.0f / scale_h;
    int srow = t >> 3, sch = t & 7;
    const float* hbase[4];
#pragma unroll
    for (int p = 0; p < 4; p++) {
        int gr = mtile * 128 + p * 32 + srow; if (gr >= NN) gr = NN - 1;
        hbase[p] = g_h + (size_t)gr * HID + sch * 8;
    }

    f32x4 acc[2][3] = {};
#pragma unroll 1
    for (int kit = 0; kit < 4; kit++) {
        if (kit) __syncthreads();
#pragma unroll
        for (int p = 0; p < 4; p++) {
            int row = p * 32 + srow;
            f32x4 v0 = *(const f32x4*)(hbase[p] + kit * 64);
            f32x4 v1 = *(const f32x4*)(hbase[p] + kit * 64 + 4);
            bf16x8 o;
            o[0] = quant1(v0.x, rs); o[1] = quant1(v0.y, rs);
            o[2] = quant1(v0.z, rs); o[3] = quant1(v0.w, rs);
            o[4] = quant1(v1.x, rs); o[5] = quant1(v1.y, rs);
            o[6] = quant1(v1.z, rs); o[7] = quant1(v1.w, rs);
            *(bf16x8*)(lA2 + row * LDK + sch * 8) = o;
        }
        __syncthreads();   // also orders the one-time lB2 fill before first use
#pragma unroll
        for (int k32 = 0; k32 < 2; k32++) {
            int csA = (k32 * 4 + quad) * 8;
            int chB = (kit * 8 + k32 * 4 + quad) * 8;
            bf16x8 a[2], b[3];
#pragma unroll
            for (int i = 0; i < 2; i++)
                a[i] = *(const bf16x8*)(lA2 + (wv * 32 + i * 16 + l16) * LDK + csA);
#pragma unroll
            for (int j = 0; j < 3; j++)
                b[j] = *(const bf16x8*)(lB2 + (j * 16 + l16) * LDB2 + chB);
#pragma unroll
            for (int i = 0; i < 2; i++)
#pragma unroll
                for (int j = 0; j < 3; j++)
                    acc[i][j] = __builtin_amdgcn_mfma_f32_16x16x32_bf16(a[i], b[j], acc[i][j], 0, 0, 0);
        }
    }
    float s = scale_h * (__uint_as_float(g_amax_bits[2]) / 127.0f + 1e-12f);
#pragma unroll
    for (int j = 0; j < 3; j++) {
        int col = j * 16 + l16;
        float bias = (col < OC) ? b2[col] : 0.0f;
#pragma unroll
        for (int i = 0; i < 2; i++) {
#pragma unroll
            for (int r = 0; r < 4; r++) {
                int grow = mtile * 128 + wv * 32 + i * 16 + quad * 4 + r;
                if (col < OC && grow < NN)
                    g_z[(size_t)grow * OC + col] = s * acc[i][j][r] + bias;
            }
        }
    }
}

// ---------------- gather + fused log_softmax: one wave per node ----------------
__launch_bounds__(256)
__global__ void gather_kernel(float* __restrict__ out) {
    int node = (blockIdx.x * 256 + threadIdx.x) >> 6;
    int lane = threadIdx.x & 63;
    if (node >= NN) return;
    unsigned e0 = g_rowstart[node], e1 = g_rowstart[node + 1];
    float dinvd = g_dinv[node];
    float acc = 0.0f;
    unsigned e = e0;
    for (; e + 2 <= e1; e += 2) {
        int s0 = g_csr_src[e], s1 = g_csr_src[e + 1];
        float c0 = g_dinv[s0] * dinvd;
        float c1 = g_dinv[s1] * dinvd;
        float z0 = (lane < OC) ? g_z[(size_t)s0 * OC + lane] : 0.0f;
        float z1 = (lane < OC) ? g_z[(size_t)s1 * OC + lane] : 0.0f;
        acc += z0 * c0 + z1 * c1;
    }
    if (e < e1) {
        int s0 = g_csr_src[e];
        float c0 = g_dinv[s0] * dinvd;
        float z0 = (lane < OC) ? g_z[(size_t)s0 * OC + lane] : 0.0f;
        acc += z0 * c0;
    }
    float m = (lane < OC) ? acc : -1e30f;
#pragma unroll
    for (int off = 32; off > 0; off >>= 1) m = fmaxf(m, __shfl_xor(m, off, 64));
    float ex = (lane < OC) ? __expf(acc - m) : 0.0f;
    float ssum = ex;
#pragma unroll
    for (int off = 32; off > 0; off >>= 1) ssum += __shfl_xor(ssum, off, 64);
    float lg = __logf(ssum);
    if (lane < OC) out[(size_t)node * OC + lane] = acc - m - lg;
}

extern "C" void kernel_launch(void* const* d_in, const int* in_sizes, int n_in,
                              void* d_out, int out_size, void* d_ws, size_t ws_size,
                              hipStream_t stream) {
    const float* x  = (const float*)d_in[0];
    const int*   ei = (const int*)d_in[1];
    const float* w1 = (const float*)d_in[2];
    const float* b1 = (const float*)d_in[3];
    const float* w2 = (const float*)d_in[4];
    const float* b2 = (const float*)d_in[5];
    float* out = (float*)d_out;
    (void)d_ws; (void)ws_size; (void)in_sizes; (void)n_in; (void)out_size;

    init_kernel<<<1024, 256, 0, stream>>>();
    // topology pipeline: two-level binned CSR build
    chist_kernel<<<128, 256, 0, stream>>>(ei);
    cscan_kernel<<<1, 512, 0, stream>>>();
    bin_kernel<<<BIN_BLOCKS, 256, 0, stream>>>(ei);
    local_kernel<<<NBKT, 256, 0, stream>>>();
    // feature pipeline
    absmax_kernel<<<2048, 256, 0, stream>>>(x,  (NN * INC) / 4, 0);
    absmax_kernel<<<128, 256, 0, stream>>>(w1, (HID * INC) / 4, 1);
    absmax_kernel<<<10, 256, 0, stream>>>(w2,  (OC * HID) / 4, 2);
    quantw_kernel<<<128, 256, 0, stream>>>(w1, (HID * INC) / 4, 1, 0);
    quantw_kernel<<<10, 256, 0, stream>>>(w2,  (OC * HID) / 4, 2, 1);
    gemm1_kernel<<<((NN + 127) / 128) * 2, 256, 0, stream>>>(x, b1);
    gemm2_kernel<<<(NN + 127) / 128, 256, 0, stream>>>(b2);
    gather_kernel<<<(NN + 3) / 4, 256, 0, stream>>>(out);
}

// Round 7
// 634.791 us; speedup vs baseline: 6.3968x; 1.0122x over previous
//
#include <hip/hip_runtime.h>
#include <hip/hip_bf16.h>
#include <stdint.h>
#include <stddef.h>

#define NN   100000   // nodes
#define NE   1600000  // edges
#define INC  512      // in channels
#define HID  256      // hidden
#define OC   40       // out channels
#define OCP  48       // padded out channels (3 x 16 col-tiles)

#define LDK  72       // padded LDS row stride (64 + 8): bank-conflict-free
#define LDB2 264      // padded lB2 row stride (256 + 8)

#define NBKT ((NN + 255) / 256)   // 391 coarse buckets of 256 nodes

typedef __bf16 bf16_t;
typedef __bf16 bf16x8 __attribute__((ext_vector_type(8)));
typedef __bf16 bf16x4 __attribute__((ext_vector_type(4)));
typedef float  f32x4  __attribute__((ext_vector_type(4)));

// ---- device-global scratch ----
__device__ unsigned g_amax_bits[4];          // 0:x 1:w1 2:w2 3:h
__device__ float    g_dinv[NN];
__device__ bf16_t   g_qw1[HID * INC];
__device__ bf16_t   g_qw2[OCP * HID];        // rows 40..47 zero
__device__ float    g_h[(size_t)NN * HID];   // relu(fc1) fp32
__device__ float    g_z[(size_t)NN * OC];    // fc2 output (16 MB -> L2/L3 resident)
// CSR-by-destination (two-level binned build)
__device__ unsigned g_chist[NBKT];
__device__ unsigned g_cstart[NBKT + 1];
__device__ unsigned g_ccur[NBKT];
__device__ uint2    g_bin[NE];               // (src, dst) grouped by coarse bucket
__device__ unsigned g_rowstart[NN + 1];
__device__ int      g_csr_src[NE];

__device__ __forceinline__ bf16_t quant1(float v, float rs) {
    return (bf16_t)fminf(fmaxf(rintf(v * rs), -128.0f), 127.0f);
}

// ---------------- init ----------------
__global__ void init_kernel() {
    int idx = blockIdx.x * blockDim.x + threadIdx.x;
    int stride = gridDim.x * blockDim.x;
    for (int i = idx; i < NBKT; i += stride) g_chist[i] = 0u;
    for (int i = idx; i < OCP * HID; i += stride) g_qw2[i] = (bf16_t)0.0f;
    if (idx < 4) g_amax_bits[idx] = 0u;
}

// ---------------- coarse histogram: 391 buckets, LDS-aggregated ----------------
__global__ void chist_kernel(const int* __restrict__ ei) {
    const int* dst = ei + NE;
    __shared__ unsigned hist[NBKT];
    int t = threadIdx.x;
    for (int i = t; i < NBKT; i += 256) hist[i] = 0u;
    __syncthreads();
    int idx = blockIdx.x * 256 + t;
    int stride = gridDim.x * 256;
    for (int e = idx; e < NE; e += stride) atomicAdd(&hist[dst[e] >> 8], 1u);
    __syncthreads();
    for (int i = t; i < NBKT; i += 256) {
        unsigned c = hist[i];
        if (c) atomicAdd(&g_chist[i], c);
    }
}

// ---------------- coarse scan (1 block, 512 threads = 8 waves) ----------------
__global__ void cscan_kernel() {
    int t = threadIdx.x;
    unsigned v = (t < NBKT) ? g_chist[t] : 0u;
    int lane = t & 63, wv = t >> 6;
    unsigned sc = v;
#pragma unroll
    for (int off = 1; off < 64; off <<= 1) {
        unsigned n = __shfl_up(sc, off, 64);
        if (lane >= off) sc += n;
    }
    __shared__ unsigned ws[8];
    if (lane == 63) ws[wv] = sc;
    __syncthreads();
    unsigned woff = 0;
    for (int w = 0; w < 8; w++) if (w < wv) woff += ws[w];
    unsigned excl = woff + sc - v;
    if (t < NBKT) { g_cstart[t] = excl; g_ccur[t] = excl; }
    if (t == 0) g_cstart[NBKT] = NE;
}

// ---------------- bin: group edges by coarse bucket (block-local LDS sort) ----------------
#define BIN_BLOCKS 200
#define BIN_EPB    (NE / BIN_BLOCKS)   // 8000
__global__ void bin_kernel(const int* __restrict__ ei) {
    const int* srcp = ei;
    const int* dstp = ei + NE;
    __shared__ unsigned hist[NBKT];
    __shared__ unsigned base[NBKT];
    int t = threadIdx.x;
    int e0 = blockIdx.x * BIN_EPB, e1 = e0 + BIN_EPB;
    for (int i = t; i < NBKT; i += 256) hist[i] = 0u;
    __syncthreads();
    for (int e = e0 + t; e < e1; e += 256) atomicAdd(&hist[dstp[e] >> 8], 1u);
    __syncthreads();
    for (int i = t; i < NBKT; i += 256) {
        unsigned c = hist[i];
        base[i] = c ? atomicAdd(&g_ccur[i], c) : 0u;
        hist[i] = 0u;   // reuse as local cursor
    }
    __syncthreads();
    for (int e = e0 + t; e < e1; e += 256) {
        int d = dstp[e], s = srcp[e];
        int b = d >> 8;
        unsigned r = atomicAdd(&hist[b], 1u);
        g_bin[base[b] + r] = make_uint2((unsigned)s, (unsigned)d);
    }
}

// ---------------- local: per-bucket node histogram -> rowstart/dinv/csr_src ----------------
__global__ void local_kernel() {
    int b = blockIdx.x, t = threadIdx.x;
    unsigned e0 = g_cstart[b], e1 = g_cstart[b + 1];
    __shared__ unsigned hist[256];
    __shared__ unsigned curs[256];
    __shared__ unsigned wsum[4];
    hist[t] = 0u;
    __syncthreads();
    for (unsigned e = e0 + t; e < e1; e += 256) atomicAdd(&hist[g_bin[e].y & 255], 1u);
    __syncthreads();
    unsigned v = hist[t];
    int lane = t & 63, wv = t >> 6;
    unsigned sc = v;
#pragma unroll
    for (int off = 1; off < 64; off <<= 1) {
        unsigned n = __shfl_up(sc, off, 64);
        if (lane >= off) sc += n;
    }
    if (lane == 63) wsum[wv] = sc;
    __syncthreads();
    unsigned woff = 0;
    for (int w = 0; w < 4; w++) if (w < wv) woff += wsum[w];
    unsigned excl = woff + sc - v;
    int node = b * 256 + t;
    if (node < NN) {
        g_rowstart[node] = e0 + excl;
        g_dinv[node] = v ? rsqrtf((float)v) : 0.0f;
    }
    if (b == 0 && t == 0) g_rowstart[NN] = NE;
    curs[t] = excl;
    __syncthreads();
    for (unsigned e = e0 + t; e < e1; e += 256) {
        uint2 ed = g_bin[e];
        unsigned r = atomicAdd(&curs[ed.y & 255], 1u);
        g_csr_src[e0 + r] = (int)ed.x;
    }
}

// ---------------- absmax reduction ----------------
__global__ void absmax_kernel(const float* __restrict__ src, int n4, int slot) {
    int idx = blockIdx.x * blockDim.x + threadIdx.x;
    int stride = gridDim.x * blockDim.x;
    const f32x4* s4 = (const f32x4*)src;
    float m = 0.0f;
    for (int i = idx; i < n4; i += stride) {
        f32x4 v = s4[i];
        m = fmaxf(m, fmaxf(fmaxf(fabsf(v.x), fabsf(v.y)),
                           fmaxf(fabsf(v.z), fabsf(v.w))));
    }
#pragma unroll
    for (int off = 32; off > 0; off >>= 1) m = fmaxf(m, __shfl_xor(m, off, 64));
    __shared__ float sm[4];
    if ((threadIdx.x & 63) == 0) sm[threadIdx.x >> 6] = m;
    __syncthreads();
    if (threadIdx.x == 0) {
        float mm = fmaxf(fmaxf(sm[0], sm[1]), fmaxf(sm[2], sm[3]));
        atomicMax(&g_amax_bits[slot], __float_as_uint(mm));
    }
}

// ------------- quantize weights to bf16-exact ints -------------
__global__ void quantw_kernel(const float* __restrict__ src, int n4, int slot, int which) {
    bf16_t* dst = which ? g_qw2 : g_qw1;
    float rs = 1.0f / (__uint_as_float(g_amax_bits[slot]) / 127.0f + 1e-12f);
    int idx = blockIdx.x * blockDim.x + threadIdx.x;
    int stride = gridDim.x * blockDim.x;
    const f32x4* s4 = (const f32x4*)src;
    bf16x4* d4 = (bf16x4*)dst;
    for (int i = idx; i < n4; i += stride) {
        f32x4 v = s4[i];
        bf16x4 o;
        o[0] = quant1(v.x, rs); o[1] = quant1(v.y, rs);
        o[2] = quant1(v.z, rs); o[3] = quant1(v.w, rs);
        d4[i] = o;
    }
}

// ---------------- GEMM1 fused: h = relu(fq(x) @ qw1^T * s + b1), amax(h) ----------------
// 128x128 tile, BK=64, padded stride 72, DOUBLE-BUFFERED LDS + register prefetch.
// One barrier per kit. Safety: W(k+1) on buf[b] and last read R(k-1) of buf[b]
// are separated by barrier B_k (every wave's R(k-1) precedes its W(k) < B_k;
// every wave's W(k+1) follows B_k).
__launch_bounds__(256)
__global__ void gemm1_kernel(const float* __restrict__ x, const float* __restrict__ b1) {
    __shared__ bf16_t lA[2][128 * LDK];
    __shared__ bf16_t lB[2][128 * LDK];
    int t = threadIdx.x;
    int mtile = blockIdx.x >> 1, ntile = blockIdx.x & 1;
    int lane = t & 63, wv = t >> 6;
    int quad = lane >> 4, l16 = lane & 15;
    int mq = wv >> 1, nq = wv & 1;

    float scale_x = __uint_as_float(g_amax_bits[0]) / 127.0f + 1e-12f;
    float rs = 1.0f / scale_x;

    int srow = t >> 3;     // 0..31
    int sch  = t & 7;      // 16B chunk 0..7

    const float*  xbase[4];
    const bf16_t* wbase[4];
#pragma unroll
    for (int p = 0; p < 4; p++) {
        int gr = mtile * 128 + p * 32 + srow; if (gr >= NN) gr = NN - 1;
        xbase[p] = x + (size_t)gr * INC + sch * 8;
        wbase[p] = g_qw1 + (size_t)(ntile * 128 + p * 32 + srow) * INC + sch * 8;
    }

    // preload kit 0 into registers
    f32x4 av[4][2]; bf16x8 bv[4];
#pragma unroll
    for (int p = 0; p < 4; p++) {
        av[p][0] = *(const f32x4*)(xbase[p]);
        av[p][1] = *(const f32x4*)(xbase[p] + 4);
        bv[p]    = *(const bf16x8*)(wbase[p]);
    }

    f32x4 acc[4][4] = {};
#pragma unroll 1
    for (int kit = 0; kit < 8; kit++) {
        int bs = kit & 1;
        // stage current kit from registers into buf[bs]
#pragma unroll
        for (int p = 0; p < 4; p++) {
            int row = p * 32 + srow;
            bf16x8 o;
            o[0] = quant1(av[p][0].x, rs); o[1] = quant1(av[p][0].y, rs);
            o[2] = quant1(av[p][0].z, rs); o[3] = quant1(av[p][0].w, rs);
            o[4] = quant1(av[p][1].x, rs); o[5] = quant1(av[p][1].y, rs);
            o[6] = quant1(av[p][1].z, rs); o[7] = quant1(av[p][1].w, rs);
            *(bf16x8*)(lA[bs] + row * LDK + sch * 8) = o;
            *(bf16x8*)(lB[bs] + row * LDK + sch * 8) = bv[p];
        }
        // prefetch kit+1 into registers (VGPR-only: no vmcnt drain at the barrier;
        // the wait lands at next kit's staging, overlapping this kit's MFMA)
        if (kit + 1 < 8) {
#pragma unroll
            for (int p = 0; p < 4; p++) {
                av[p][0] = *(const f32x4*)(xbase[p] + (kit + 1) * 64);
                av[p][1] = *(const f32x4*)(xbase[p] + (kit + 1) * 64 + 4);
                bv[p]    = *(const bf16x8*)(wbase[p] + (kit + 1) * 64);
            }
        }
        __syncthreads();
#pragma unroll
        for (int k32 = 0; k32 < 2; k32++) {
            int cs = (k32 * 4 + quad) * 8;
            bf16x8 a[4], b[4];
#pragma unroll
            for (int i = 0; i < 4; i++)
                a[i] = *(const bf16x8*)(lA[bs] + (mq * 64 + i * 16 + l16) * LDK + cs);
#pragma unroll
            for (int j = 0; j < 4; j++)
                b[j] = *(const bf16x8*)(lB[bs] + (nq * 64 + j * 16 + l16) * LDK + cs);
#pragma unroll
            for (int i = 0; i < 4; i++)
#pragma unroll
                for (int j = 0; j < 4; j++)
                    acc[i][j] = __builtin_amdgcn_mfma_f32_16x16x32_bf16(a[i], b[j], acc[i][j], 0, 0, 0);
        }
    }
    float s = scale_x * (__uint_as_float(g_amax_bits[1]) / 127.0f + 1e-12f);
    float lmax = 0.0f;
#pragma unroll
    for (int j = 0; j < 4; j++) {
        int col = ntile * 128 + nq * 64 + j * 16 + l16;
        float bias = b1[col];
#pragma unroll
        for (int i = 0; i < 4; i++) {
#pragma unroll
            for (int r = 0; r < 4; r++) {
                int grow = mtile * 128 + mq * 64 + i * 16 + quad * 4 + r;
                float v = fmaxf(s * acc[i][j][r] + bias, 0.0f);
                lmax = fmaxf(lmax, v);
                if (grow < NN) g_h[(size_t)grow * HID + col] = v;
            }
        }
    }
#pragma unroll
    for (int off = 32; off > 0; off >>= 1) lmax = fmaxf(lmax, __shfl_xor(lmax, off, 64));
    if (lane == 0) atomicMax(&g_amax_bits[3], __float_as_uint(lmax));
}

// ---------------- GEMM2 fused: z = fq(h) @ qw2^T * s + b2 ----------------
__launch_bounds__(256)
__global__ void gemm2_kernel(const float* __restrict__ b2) {
    __shared__ bf16_t lB2[OCP * LDB2];
    __shared__ bf16_t lA2[128 * LDK];
    int t = threadIdx.x;
    int mtile = blockIdx.x;
    int lane = t & 63, wv = t >> 6;
    int quad = lane >> 4, l16 = lane & 15;

#pragma unroll
    for (int p = 0; p < 6; p++) {
        int ci = p * 256 + t;             // 0..1535 chunks of 8 elements
        int row = ci >> 5, ch = ci & 31;
        *(bf16x8*)(lB2 + row * LDB2 + ch * 8) =
            *(const bf16x8*)(g_qw2 + row * 256 + ch * 8);
    }

    float scale_h = __uint_as_float(g_amax_bits[3]) / 127.0f + 1e-12f;
    float rs = 1.0f / scale_h;
    int srow = t >> 3, sch = t & 7;
    const float* hbase[4];
#pragma unroll
    for (int p = 0; p < 4; p++) {
        int gr = mtile * 128 + p * 32 + srow; if (gr >= NN) gr = NN - 1;
        hbase[p] = g_h + (size_t)gr * HID + sch * 8;
    }

    f32x4 acc[2][3] = {};
#pragma unroll 1
    for (int kit = 0; kit < 4; kit++) {
        if (kit) __syncthreads();
#pragma unroll
        for (int p = 0; p < 4; p++) {
            int row = p * 32 + srow;
            f32x4 v0 = *(const f32x4*)(hbase[p] + kit * 64);
            f32x4 v1 = *(const f32x4*)(hbase[p] + kit * 64 + 4);
            bf16x8 o;
            o[0] = quant1(v0.x, rs); o[1] = quant1(v0.y, rs);
            o[2] = quant1(v0.z, rs); o[3] = quant1(v0.w, rs);
            o[4] = quant1(v1.x, rs); o[5] = quant1(v1.y, rs);
            o[6] = quant1(v1.z, rs); o[7] = quant1(v1.w, rs);
            *(bf16x8*)(lA2 + row * LDK + sch * 8) = o;
        }
        __syncthreads();   // also orders the one-time lB2 fill before first use
#pragma unroll
        for (int k32 = 0; k32 < 2; k32++) {
            int csA = (k32 * 4 + quad) * 8;
            int chB = (kit * 8 + k32 * 4 + quad) * 8;
            bf16x8 a[2], b[3];
#pragma unroll
            for (int i = 0; i < 2; i++)
                a[i] = *(const bf16x8*)(lA2 + (wv * 32 + i * 16 + l16) * LDK + csA);
#pragma unroll
            for (int j = 0; j < 3; j++)
                b[j] = *(const bf16x8*)(lB2 + (j * 16 + l16) * LDB2 + chB);
#pragma unroll
            for (int i = 0; i < 2; i++)
#pragma unroll
                for (int j = 0; j < 3; j++)
                    acc[i][j] = __builtin_amdgcn_mfma_f32_16x16x32_bf16(a[i], b[j], acc[i][j], 0, 0, 0);
        }
    }
    float s = scale_h * (__uint_as_float(g_amax_bits[2]) / 127.0f + 1e-12f);
#pragma unroll
    for (int j = 0; j < 3; j++) {
        int col = j * 16 + l16;
        float bias = (col < OC) ? b2[col] : 0.0f;
#pragma unroll
        for (int i = 0; i < 2; i++) {
#pragma unroll
            for (int r = 0; r < 4; r++) {
                int grow = mtile * 128 + wv * 32 + i * 16 + quad * 4 + r;
                if (col < OC && grow < NN)
                    g_z[(size_t)grow * OC + col] = s * acc[i][j][r] + bias;
            }
        }
    }
}

// ---------------- gather + fused log_softmax: one wave per node ----------------
__launch_bounds__(256)
__global__ void gather_kernel(float* __restrict__ out) {
    int node = (blockIdx.x * 256 + threadIdx.x) >> 6;
    int lane = threadIdx.x & 63;
    if (node >= NN) return;
    unsigned e0 = g_rowstart[node], e1 = g_rowstart[node + 1];
    float dinvd = g_dinv[node];
    float acc = 0.0f;
    unsigned e = e0;
    for (; e + 2 <= e1; e += 2) {
        int s0 = g_csr_src[e], s1 = g_csr_src[e + 1];
        float c0 = g_dinv[s0] * dinvd;
        float c1 = g_dinv[s1] * dinvd;
        float z0 = (lane < OC) ? g_z[(size_t)s0 * OC + lane] : 0.0f;
        float z1 = (lane < OC) ? g_z[(size_t)s1 * OC + lane] : 0.0f;
        acc += z0 * c0 + z1 * c1;
    }
    if (e < e1) {
        int s0 = g_csr_src[e];
        float c0 = g_dinv[s0] * dinvd;
        float z0 = (lane < OC) ? g_z[(size_t)s0 * OC + lane] : 0.0f;
        acc += z0 * c0;
    }
    float m = (lane < OC) ? acc : -1e30f;
#pragma unroll
    for (int off = 32; off > 0; off >>= 1) m = fmaxf(m, __shfl_xor(m, off, 64));
    float ex = (lane < OC) ? __expf(acc - m) : 0.0f;
    float ssum = ex;
#pragma unroll
    for (int off = 32; off > 0; off >>= 1) ssum += __shfl_xor(ssum, off, 64);
    float lg = __logf(ssum);
    if (lane < OC) out[(size_t)node * OC + lane] = acc - m - lg;
}

extern "C" void kernel_launch(void* const* d_in, const int* in_sizes, int n_in,
                              void* d_out, int out_size, void* d_ws, size_t ws_size,
                              hipStream_t stream) {
    const float* x  = (const float*)d_in[0];
    const int*   ei = (const int*)d_in[1];
    const float* w1 = (const float*)d_in[2];
    const float* b1 = (const float*)d_in[3];
    const float* w2 = (const float*)d_in[4];
    const float* b2 = (const float*)d_in[5];
    float* out = (float*)d_out;
    (void)d_ws; (void)ws_size; (void)in_sizes; (void)n_in; (void)out_size;

    init_kernel<<<1024, 256, 0, stream>>>();
    // topology pipeline: two-level binned CSR build
    chist_kernel<<<128, 256, 0, stream>>>(ei);
    cscan_kernel<<<1, 512, 0, stream>>>();
    bin_kernel<<<BIN_BLOCKS, 256, 0, stream>>>(ei);
    local_kernel<<<NBKT, 256, 0, stream>>>();
    // feature pipeline
    absmax_kernel<<<2048, 256, 0, stream>>>(x,  (NN * INC) / 4, 0);
    absmax_kernel<<<128, 256, 0, stream>>>(w1, (HID * INC) / 4, 1);
    absmax_kernel<<<10, 256, 0, stream>>>(w2,  (OC * HID) / 4, 2);
    quantw_kernel<<<128, 256, 0, stream>>>(w1, (HID * INC) / 4, 1, 0);
    quantw_kernel<<<10, 256, 0, stream>>>(w2,  (OC * HID) / 4, 2, 1);
    gemm1_kernel<<<((NN + 127) / 128) * 2, 256, 0, stream>>>(x, b1);
    gemm2_kernel<<<(NN + 127) / 128, 256, 0, stream>>>(b2);
    gather_kernel<<<(NN + 3) / 4, 256, 0, stream>>>(out);
}

// Round 8
// 606.292 us; speedup vs baseline: 6.6975x; 1.0470x over previous
//
#include <hip/hip_runtime.h>
#include <hip/hip_bf16.h>
#include <stdint.h>
#include <stddef.h>

#define NN   100000   // nodes
#define NE   1600000  // edges
#define INC  512      // in channels
#define HID  256      // hidden
#define OC   40       // out channels
#define OCP  48       // padded out channels (3 x 16 col-tiles)

#define LDS1 144      // int8 tile row stride in bytes (128 + 16): conflict-free
#define LDSB2 272     // lB2 row stride bytes (256 + 16)

#define NBKT ((NN + 255) / 256)   // 391 coarse buckets of 256 nodes

typedef float  f32x4  __attribute__((ext_vector_type(4)));
typedef int    i32x4  __attribute__((ext_vector_type(4)));

// ---- device-global scratch ----
__device__ unsigned g_amax_bits[4];          // 0:x 1:w1 2:w2 3:h
__device__ float    g_dinv[NN];
__device__ signed char g_qx[(size_t)NN * INC];   // 51.2 MB int8 quantized x
__device__ signed char g_qw1[HID * INC];         // int8
__device__ signed char g_qw2[OCP * HID];         // int8, rows 40..47 zero
__device__ float    g_h[(size_t)NN * HID];   // relu(fc1) fp32
__device__ float    g_z[(size_t)NN * OC];    // fc2 output
// CSR-by-destination (two-level binned build)
__device__ unsigned g_chist[NBKT];
__device__ unsigned g_cstart[NBKT + 1];
__device__ unsigned g_ccur[NBKT];
__device__ uint2    g_bin[NE];
__device__ unsigned g_rowstart[NN + 1];
__device__ int      g_csr_src[NE];

__device__ __forceinline__ float quantf(float v, float rs) {
    return fminf(fmaxf(rintf(v * rs), -128.0f), 127.0f);
}
__device__ __forceinline__ int pack4(float a, float b, float c, float d, float rs) {
    int q0 = (int)quantf(a, rs), q1 = (int)quantf(b, rs);
    int q2 = (int)quantf(c, rs), q3 = (int)quantf(d, rs);
    return (q0 & 255) | ((q1 & 255) << 8) | ((q2 & 255) << 16) | ((q3 & 255) << 24);
}

// ---------------- init ----------------
__global__ void init_kernel() {
    int idx = blockIdx.x * blockDim.x + threadIdx.x;
    int stride = gridDim.x * blockDim.x;
    for (int i = idx; i < NBKT; i += stride) g_chist[i] = 0u;
    for (int i = idx; i < (OCP * HID) / 4; i += stride) ((int*)g_qw2)[i] = 0;
    if (idx < 4) g_amax_bits[idx] = 0u;
}

// ---------------- coarse histogram ----------------
__global__ void chist_kernel(const int* __restrict__ ei) {
    const int* dst = ei + NE;
    __shared__ unsigned hist[NBKT];
    int t = threadIdx.x;
    for (int i = t; i < NBKT; i += 256) hist[i] = 0u;
    __syncthreads();
    int idx = blockIdx.x * 256 + t;
    int stride = gridDim.x * 256;
    for (int e = idx; e < NE; e += stride) atomicAdd(&hist[dst[e] >> 8], 1u);
    __syncthreads();
    for (int i = t; i < NBKT; i += 256) {
        unsigned c = hist[i];
        if (c) atomicAdd(&g_chist[i], c);
    }
}

// ---------------- coarse scan ----------------
__global__ void cscan_kernel() {
    int t = threadIdx.x;
    unsigned v = (t < NBKT) ? g_chist[t] : 0u;
    int lane = t & 63, wv = t >> 6;
    unsigned sc = v;
#pragma unroll
    for (int off = 1; off < 64; off <<= 1) {
        unsigned n = __shfl_up(sc, off, 64);
        if (lane >= off) sc += n;
    }
    __shared__ unsigned ws[8];
    if (lane == 63) ws[wv] = sc;
    __syncthreads();
    unsigned woff = 0;
    for (int w = 0; w < 8; w++) if (w < wv) woff += ws[w];
    unsigned excl = woff + sc - v;
    if (t < NBKT) { g_cstart[t] = excl; g_ccur[t] = excl; }
    if (t == 0) g_cstart[NBKT] = NE;
}

// ---------------- bin: group edges by coarse bucket ----------------
#define BIN_BLOCKS 400
#define BIN_EPB    (NE / BIN_BLOCKS)   // 4000
__global__ void bin_kernel(const int* __restrict__ ei) {
    const int* srcp = ei;
    const int* dstp = ei + NE;
    __shared__ unsigned hist[NBKT];
    __shared__ unsigned base[NBKT];
    int t = threadIdx.x;
    int e0 = blockIdx.x * BIN_EPB, e1 = e0 + BIN_EPB;
    for (int i = t; i < NBKT; i += 256) hist[i] = 0u;
    __syncthreads();
    for (int e = e0 + t; e < e1; e += 256) atomicAdd(&hist[dstp[e] >> 8], 1u);
    __syncthreads();
    for (int i = t; i < NBKT; i += 256) {
        unsigned c = hist[i];
        base[i] = c ? atomicAdd(&g_ccur[i], c) : 0u;
        hist[i] = 0u;   // reuse as local cursor
    }
    __syncthreads();
    for (int e = e0 + t; e < e1; e += 256) {
        int d = dstp[e], s = srcp[e];
        int b = d >> 8;
        unsigned r = atomicAdd(&hist[b], 1u);
        g_bin[base[b] + r] = make_uint2((unsigned)s, (unsigned)d);
    }
}

// ---------------- local: per-bucket -> rowstart/dinv/csr_src ----------------
__global__ void local_kernel() {
    int b = blockIdx.x, t = threadIdx.x;
    unsigned e0 = g_cstart[b], e1 = g_cstart[b + 1];
    __shared__ unsigned hist[256];
    __shared__ unsigned curs[256];
    __shared__ unsigned wsum[4];
    hist[t] = 0u;
    __syncthreads();
    for (unsigned e = e0 + t; e < e1; e += 256) atomicAdd(&hist[g_bin[e].y & 255], 1u);
    __syncthreads();
    unsigned v = hist[t];
    int lane = t & 63, wv = t >> 6;
    unsigned sc = v;
#pragma unroll
    for (int off = 1; off < 64; off <<= 1) {
        unsigned n = __shfl_up(sc, off, 64);
        if (lane >= off) sc += n;
    }
    if (lane == 63) wsum[wv] = sc;
    __syncthreads();
    unsigned woff = 0;
    for (int w = 0; w < 4; w++) if (w < wv) woff += wsum[w];
    unsigned excl = woff + sc - v;
    int node = b * 256 + t;
    if (node < NN) {
        g_rowstart[node] = e0 + excl;
        g_dinv[node] = v ? rsqrtf((float)v) : 0.0f;
    }
    if (b == 0 && t == 0) g_rowstart[NN] = NE;
    curs[t] = excl;
    __syncthreads();
    for (unsigned e = e0 + t; e < e1; e += 256) {
        uint2 ed = g_bin[e];
        unsigned r = atomicAdd(&curs[ed.y & 255], 1u);
        g_csr_src[e0 + r] = (int)ed.x;
    }
}

// ---------------- absmax reduction ----------------
__global__ void absmax_kernel(const float* __restrict__ src, int n4, int slot) {
    int idx = blockIdx.x * blockDim.x + threadIdx.x;
    int stride = gridDim.x * blockDim.x;
    const f32x4* s4 = (const f32x4*)src;
    float m = 0.0f;
    for (int i = idx; i < n4; i += stride) {
        f32x4 v = s4[i];
        m = fmaxf(m, fmaxf(fmaxf(fabsf(v.x), fabsf(v.y)),
                           fmaxf(fabsf(v.z), fabsf(v.w))));
    }
#pragma unroll
    for (int off = 32; off > 0; off >>= 1) m = fmaxf(m, __shfl_xor(m, off, 64));
    __shared__ float sm[4];
    if ((threadIdx.x & 63) == 0) sm[threadIdx.x >> 6] = m;
    __syncthreads();
    if (threadIdx.x == 0) {
        float mm = fmaxf(fmaxf(sm[0], sm[1]), fmaxf(sm[2], sm[3]));
        atomicMax(&g_amax_bits[slot], __float_as_uint(mm));
    }
}

// ---------------- quantize x to int8 (streaming, 16 elems/thread/iter) ----------------
__global__ void quantx_kernel(const float* __restrict__ src, int n16) {
    float rs = 1.0f / (__uint_as_float(g_amax_bits[0]) / 127.0f + 1e-12f);
    int idx = blockIdx.x * blockDim.x + threadIdx.x;
    int stride = gridDim.x * blockDim.x;
    i32x4* d = (i32x4*)g_qx;
    for (int i = idx; i < n16; i += stride) {
        const f32x4* s = (const f32x4*)(src + (size_t)i * 16);
        f32x4 v0 = s[0], v1 = s[1], v2 = s[2], v3 = s[3];
        i32x4 o;
        o[0] = pack4(v0.x, v0.y, v0.z, v0.w, rs);
        o[1] = pack4(v1.x, v1.y, v1.z, v1.w, rs);
        o[2] = pack4(v2.x, v2.y, v2.z, v2.w, rs);
        o[3] = pack4(v3.x, v3.y, v3.z, v3.w, rs);
        d[i] = o;
    }
}

// ---------------- quantize weights to int8 ----------------
__global__ void quantw8_kernel(const float* __restrict__ src, int nint, int slot, int which) {
    int* dst = which ? (int*)g_qw2 : (int*)g_qw1;
    float rs = 1.0f / (__uint_as_float(g_amax_bits[slot]) / 127.0f + 1e-12f);
    int idx = blockIdx.x * blockDim.x + threadIdx.x;
    int stride = gridDim.x * blockDim.x;
    for (int i = idx; i < nint; i += stride) {
        f32x4 v = *(const f32x4*)(src + (size_t)i * 4);
        dst[i] = pack4(v.x, v.y, v.z, v.w, rs);
    }
}

// ---------------- GEMM1: h = relu(s * (qx @ qw1^T) + b1), amax(h) ----------------
// int8 MFMA 16x16x64, 128x128 tile, BK=128 (4 kits), dbuf LDS + register prefetch.
// Same barrier-per-kit proof as R7 (write buf[b] at kit k+1 vs last read at k-1
// separated by barrier B_k).
__launch_bounds__(256)
__global__ void gemm1_kernel(const float* __restrict__ b1) {
    __shared__ char lA[2][128 * LDS1];   // 2 x 18432 B
    __shared__ char lB[2][128 * LDS1];
    int t = threadIdx.x;
    int mtile = blockIdx.x >> 1, ntile = blockIdx.x & 1;
    int lane = t & 63, wv = t >> 6;
    int quad = lane >> 4, l16 = lane & 15;
    int mq = wv >> 1, nq = wv & 1;

    int srow = t >> 3;     // 0..31
    int sch  = t & 7;      // 16B chunk 0..7

    const signed char* xb[4];
    const signed char* wb[4];
#pragma unroll
    for (int p = 0; p < 4; p++) {
        int gr = mtile * 128 + p * 32 + srow; if (gr >= NN) gr = NN - 1;
        xb[p] = g_qx + (size_t)gr * INC + sch * 16;
        wb[p] = g_qw1 + (size_t)(ntile * 128 + p * 32 + srow) * INC + sch * 16;
    }

    i32x4 av[4], bv[4];
#pragma unroll
    for (int p = 0; p < 4; p++) {
        av[p] = *(const i32x4*)(xb[p]);
        bv[p] = *(const i32x4*)(wb[p]);
    }

    i32x4 acc[4][4] = {};
#pragma unroll 1
    for (int kit = 0; kit < 4; kit++) {
        int bs = kit & 1;
#pragma unroll
        for (int p = 0; p < 4; p++) {
            int row = p * 32 + srow;
            *(i32x4*)(lA[bs] + row * LDS1 + sch * 16) = av[p];
            *(i32x4*)(lB[bs] + row * LDS1 + sch * 16) = bv[p];
        }
        if (kit + 1 < 4) {
#pragma unroll
            for (int p = 0; p < 4; p++) {
                av[p] = *(const i32x4*)(xb[p] + (kit + 1) * 128);
                bv[p] = *(const i32x4*)(wb[p] + (kit + 1) * 128);
            }
        }
        __syncthreads();
#pragma unroll
        for (int ks = 0; ks < 2; ks++) {
            int cs = ks * 64 + quad * 16;
            i32x4 a[4], b[4];
#pragma unroll
            for (int i = 0; i < 4; i++)
                a[i] = *(const i32x4*)(lA[bs] + (mq * 64 + i * 16 + l16) * LDS1 + cs);
#pragma unroll
            for (int j = 0; j < 4; j++)
                b[j] = *(const i32x4*)(lB[bs] + (nq * 64 + j * 16 + l16) * LDS1 + cs);
#pragma unroll
            for (int i = 0; i < 4; i++)
#pragma unroll
                for (int j = 0; j < 4; j++)
                    acc[i][j] = __builtin_amdgcn_mfma_i32_16x16x64_i8(a[i], b[j], acc[i][j], 0, 0, 0);
        }
    }
    float s = (__uint_as_float(g_amax_bits[0]) / 127.0f + 1e-12f)
            * (__uint_as_float(g_amax_bits[1]) / 127.0f + 1e-12f);
    float lmax = 0.0f;
#pragma unroll
    for (int j = 0; j < 4; j++) {
        int col = ntile * 128 + nq * 64 + j * 16 + l16;
        float bias = b1[col];
#pragma unroll
        for (int i = 0; i < 4; i++) {
#pragma unroll
            for (int r = 0; r < 4; r++) {
                int grow = mtile * 128 + mq * 64 + i * 16 + quad * 4 + r;
                float v = fmaxf(s * (float)acc[i][j][r] + bias, 0.0f);
                lmax = fmaxf(lmax, v);
                if (grow < NN) g_h[(size_t)grow * HID + col] = v;
            }
        }
    }
#pragma unroll
    for (int off = 32; off > 0; off >>= 1) lmax = fmaxf(lmax, __shfl_xor(lmax, off, 64));
    if (lane == 0) atomicMax(&g_amax_bits[3], __float_as_uint(lmax));
}

// ---------------- GEMM2: z = s * (fq(h) @ qw2^T) + b2 (int8 MFMA) ----------------
__launch_bounds__(256)
__global__ void gemm2_kernel(const float* __restrict__ b2) {
    __shared__ char lB2[OCP * LDSB2];   // 13056 B
    __shared__ char lA2[128 * LDS1];    // 18432 B
    int t = threadIdx.x;
    int mtile = blockIdx.x;
    int lane = t & 63, wv = t >> 6;
    int quad = lane >> 4, l16 = lane & 15;

    // load qw2 int8 (48x256 = 12288 B) into padded LDS: 768 chunks of 16 B
#pragma unroll
    for (int p = 0; p < 3; p++) {
        int ci = p * 256 + t;          // 0..767
        int row = ci >> 4, ch = ci & 15;
        *(i32x4*)(lB2 + row * LDSB2 + ch * 16) =
            *(const i32x4*)(g_qw2 + row * 256 + ch * 16);
    }

    float scale_h = __uint_as_float(g_amax_bits[3]) / 127.0f + 1e-12f;
    float rs = 1.0f / scale_h;
    int srow = t >> 3, sch = t & 7;
    const float* hbase[4];
#pragma unroll
    for (int p = 0; p < 4; p++) {
        int gr = mtile * 128 + p * 32 + srow; if (gr >= NN) gr = NN - 1;
        hbase[p] = g_h + (size_t)gr * HID + sch * 16;
    }

    i32x4 acc[2][3] = {};
#pragma unroll 1
    for (int kit = 0; kit < 2; kit++) {
        if (kit) __syncthreads();
#pragma unroll
        for (int p = 0; p < 4; p++) {
            int row = p * 32 + srow;
            const float* hp = hbase[p] + kit * 128;
            f32x4 v0 = *(const f32x4*)(hp);
            f32x4 v1 = *(const f32x4*)(hp + 4);
            f32x4 v2 = *(const f32x4*)(hp + 8);
            f32x4 v3 = *(const f32x4*)(hp + 12);
            i32x4 o;
            o[0] = pack4(v0.x, v0.y, v0.z, v0.w, rs);
            o[1] = pack4(v1.x, v1.y, v1.z, v1.w, rs);
            o[2] = pack4(v2.x, v2.y, v2.z, v2.w, rs);
            o[3] = pack4(v3.x, v3.y, v3.z, v3.w, rs);
            *(i32x4*)(lA2 + row * LDS1 + sch * 16) = o;
        }
        __syncthreads();   // also orders the one-time lB2 fill before first use
#pragma unroll
        for (int ks = 0; ks < 2; ks++) {
            int cs = ks * 64 + quad * 16;
            i32x4 a[2], b[3];
#pragma unroll
            for (int i = 0; i < 2; i++)
                a[i] = *(const i32x4*)(lA2 + (wv * 32 + i * 16 + l16) * LDS1 + cs);
#pragma unroll
            for (int j = 0; j < 3; j++)
                b[j] = *(const i32x4*)(lB2 + (j * 16 + l16) * LDSB2 + kit * 128 + cs);
#pragma unroll
            for (int i = 0; i < 2; i++)
#pragma unroll
                for (int j = 0; j < 3; j++)
                    acc[i][j] = __builtin_amdgcn_mfma_i32_16x16x64_i8(a[i], b[j], acc[i][j], 0, 0, 0);
        }
    }
    float s = scale_h * (__uint_as_float(g_amax_bits[2]) / 127.0f + 1e-12f);
#pragma unroll
    for (int j = 0; j < 3; j++) {
        int col = j * 16 + l16;
        float bias = (col < OC) ? b2[col] : 0.0f;
#pragma unroll
        for (int i = 0; i < 2; i++) {
#pragma unroll
            for (int r = 0; r < 4; r++) {
                int grow = mtile * 128 + wv * 32 + i * 16 + quad * 4 + r;
                if (col < OC && grow < NN)
                    g_z[(size_t)grow * OC + col] = s * (float)acc[i][j][r] + bias;
            }
        }
    }
}

// ---------------- gather + fused log_softmax: one wave per node ----------------
__launch_bounds__(256)
__global__ void gather_kernel(float* __restrict__ out) {
    int node = (blockIdx.x * 256 + threadIdx.x) >> 6;
    int lane = threadIdx.x & 63;
    if (node >= NN) return;
    unsigned e0 = g_rowstart[node], e1 = g_rowstart[node + 1];
    float dinvd = g_dinv[node];
    float acc = 0.0f;
    unsigned e = e0;
    for (; e + 4 <= e1; e += 4) {
        int s0 = g_csr_src[e],     s1 = g_csr_src[e + 1];
        int s2 = g_csr_src[e + 2], s3 = g_csr_src[e + 3];
        float c0 = g_dinv[s0], c1 = g_dinv[s1], c2 = g_dinv[s2], c3 = g_dinv[s3];
        float z0 = (lane < OC) ? g_z[(size_t)s0 * OC + lane] : 0.0f;
        float z1 = (lane < OC) ? g_z[(size_t)s1 * OC + lane] : 0.0f;
        float z2 = (lane < OC) ? g_z[(size_t)s2 * OC + lane] : 0.0f;
        float z3 = (lane < OC) ? g_z[(size_t)s3 * OC + lane] : 0.0f;
        acc += (z0 * c0 + z1 * c1) + (z2 * c2 + z3 * c3);
    }
    for (; e < e1; e++) {
        int s0 = g_csr_src[e];
        float z0 = (lane < OC) ? g_z[(size_t)s0 * OC + lane] : 0.0f;
        acc += z0 * g_dinv[s0];
    }
    acc *= dinvd;
    float m = (lane < OC) ? acc : -1e30f;
#pragma unroll
    for (int off = 32; off > 0; off >>= 1) m = fmaxf(m, __shfl_xor(m, off, 64));
    float ex = (lane < OC) ? __expf(acc - m) : 0.0f;
    float ssum = ex;
#pragma unroll
    for (int off = 32; off > 0; off >>= 1) ssum += __shfl_xor(ssum, off, 64);
    float lg = __logf(ssum);
    if (lane < OC) out[(size_t)node * OC + lane] = acc - m - lg;
}

extern "C" void kernel_launch(void* const* d_in, const int* in_sizes, int n_in,
                              void* d_out, int out_size, void* d_ws, size_t ws_size,
                              hipStream_t stream) {
    const float* x  = (const float*)d_in[0];
    const int*   ei = (const int*)d_in[1];
    const float* w1 = (const float*)d_in[2];
    const float* b1 = (const float*)d_in[3];
    const float* w2 = (const float*)d_in[4];
    const float* b2 = (const float*)d_in[5];
    float* out = (float*)d_out;
    (void)d_ws; (void)ws_size; (void)in_sizes; (void)n_in; (void)out_size;

    init_kernel<<<1024, 256, 0, stream>>>();
    // topology pipeline: two-level binned CSR build
    chist_kernel<<<256, 256, 0, stream>>>(ei);
    cscan_kernel<<<1, 512, 0, stream>>>();
    bin_kernel<<<BIN_BLOCKS, 256, 0, stream>>>(ei);
    local_kernel<<<NBKT, 256, 0, stream>>>();
    // feature pipeline
    absmax_kernel<<<2048, 256, 0, stream>>>(x,  (NN * INC) / 4, 0);
    absmax_kernel<<<128, 256, 0, stream>>>(w1, (HID * INC) / 4, 1);
    absmax_kernel<<<10, 256, 0, stream>>>(w2,  (OC * HID) / 4, 2);
    quantx_kernel<<<3200, 256, 0, stream>>>(x, (NN * INC) / 16);
    quantw8_kernel<<<128, 256, 0, stream>>>(w1, (HID * INC) / 4, 1, 0);
    quantw8_kernel<<<10, 256, 0, stream>>>(w2,  (OC * HID) / 4, 2, 1);
    gemm1_kernel<<<((NN + 127) / 128) * 2, 256, 0, stream>>>(b1);
    gemm2_kernel<<<(NN + 127) / 128, 256, 0, stream>>>(b2);
    gather_kernel<<<(NN + 3) / 4, 256, 0, stream>>>(out);
}